// Round 8
// baseline (1008.228 us; speedup 1.0000x reference)
//
#include <hip/hip_runtime.h>
#include <hip/hip_bf16.h>

typedef __attribute__((ext_vector_type(8))) short s8v;   // 8 bf16 = 4 VGPR
typedef __attribute__((ext_vector_type(4))) float f4v;   // MFMA acc

// A = weight frag, B = data frag  ->  C[m=unit][n=batch-row]
#define MF(A, B, C) C = __builtin_amdgcn_mfma_f32_16x16x32_bf16((A), (B), (C), 0, 0, 0)

__device__ __forceinline__ ushort f2bf(float f) {
  unsigned u = __float_as_uint(f);
  u += 0x7FFF + ((u >> 16) & 1);        // RNE (finite inputs only)
  return (ushort)(u >> 16);
}
__device__ __forceinline__ float bf2f(ushort h) {
  return __uint_as_float(((unsigned)h) << 16);
}
__device__ __forceinline__ float sigm(float p) { return 1.f / (1.f + __expf(-p)); }
__device__ __forceinline__ float tanh_safe(float a) {
  float t = __expf(-2.f * fabsf(a));
  float ng = (1.f - t) / (1.f + t);
  return a < 0.f ? -ng : ng;
}
__device__ __forceinline__ float dot4(float4 a, float4 b) {
  return fmaf(a.x, b.x, fmaf(a.y, b.y, fmaf(a.z, b.z, a.w * b.w)));
}

// ---------- pre-pass: split x into bf16 hi/lo, pad K 63->64 ----------
__global__ void conv_x(const float* __restrict__ x, ushort* __restrict__ xhi,
                       ushort* __restrict__ xlo, int total) {
  int idx = blockIdx.x * 256 + threadIdx.x;
  if (idx >= total) return;                    // total = 4096*128*16
  int k4 = (idx & 15) * 4;
  long bt = idx >> 4;
  #pragma unroll
  for (int j = 0; j < 4; ++j) {
    int k = k4 + j;
    float v = (k < 63) ? x[bt * 63 + k] : 0.f;
    ushort hi = f2bf(v);
    xhi[bt * 64 + k] = hi;
    xlo[bt * 64 + k] = f2bf(v - bf2f(hi));
  }
}

// ---------- pre-pass: pack W [384][Kreal] into per-lane frag streams (hi/lo) ----------
// frag_id = (nt*KT + kt)*2 + hl ; lane l elem i supplies W[nt*16+(l&15)][kt*32+(l>>4)*8+i]
__global__ void pack_fr(const float* __restrict__ src, ushort* __restrict__ dst,
                        int Kreal, int KT, int total) {
  int idx = blockIdx.x * 256 + threadIdx.x;
  if (idx >= total) return;
  int i = idx & 7, l = (idx >> 3) & 63, hl = (idx >> 9) & 1;
  int rest = idx >> 10;
  int kt = rest % KT, nt = rest / KT;
  int g = nt * 16 + (l & 15);
  int k = kt * 32 + (l >> 4) * 8 + i;
  float v = (k < Kreal) ? src[g * Kreal + k] : 0.f;
  ushort hi = f2bf(v);
  dst[idx] = hl ? f2bf(v - bf2f(hi)) : hi;
}

// ---------- layer 0: 16 rows/block, 16 waves (8 hi-plane + 8 lo-plane pairs) ----------
// hi-wave p: parks hi-plane frags, computes (Whi*Dh + Whi*Dl); lo-wave p: parks
// lo-plane, computes (Wlo*Dh), dumps partial C to LDS; hi adds + pointwise.
__global__ void __attribute__((amdgpu_flat_work_group_size(1024, 1024),
                               amdgpu_waves_per_eu(4, 4)))
rec_l0(const ushort* __restrict__ xhi, const ushort* __restrict__ xlo,
       const ushort* __restrict__ fih, const ushort* __restrict__ fhh,
       const float* __restrict__ bi, const float* __restrict__ bh,
       ushort* __restrict__ s_hi, ushort* __restrict__ s_lo,
       ushort* __restrict__ c_hi, ushort* __restrict__ c_lo,
       int t0, int tc, int first)
{
  __shared__ __align__(16) ushort hh_[2][2048], hl_[2][2048];  // swizzled h state
  __shared__ __align__(16) float bb[512];
  __shared__ __align__(16) ushort xs[2][2][16][76];            // x stage: buf,plane,row,col(pad)
  __shared__ __align__(16) float pd[8][4][256];                // lo-partials: pair,acc,lane*4

  const int tid = threadIdx.x;
  const int wv = tid >> 6, l = tid & 63;
  const int lr = l & 15, lg = l >> 4;
  const int isHi = (wv < 8);
  const int p = wv & 7;
  const int lsw = l ^ (l >> 3);                 // bank-conflict-free f4v slot
  const long b0 = (long)blockIdx.x * 16;

  if (tid < 128) {
    bb[tid]       = bi[tid] + bh[tid];
    bb[128 + tid] = bi[128 + tid] + bh[128 + tid];
    bb[256 + tid] = bi[256 + tid];
    bb[384 + tid] = bh[256 + tid];
  }
  const int u0 = (p << 4) + (lg << 2);
  const int hb = lr * 256 + ((u0 << 1) ^ ((lr & 7) << 4));
  if (isHi) {
    if (first) {
      *(ushort4*)((char*)hh_[0] + hb) = make_ushort4(0, 0, 0, 0);
      *(ushort4*)((char*)hl_[0] + hb) = make_ushort4(0, 0, 0, 0);
    } else {
      *(ushort4*)((char*)hh_[0] + hb) = *(const ushort4*)&c_hi[(b0 + lr) * 128 + u0];
      *(ushort4*)((char*)hl_[0] + hb) = *(const ushort4*)&c_lo[(b0 + lr) * 128 + u0];
    }
  }

  // parked weight frags (one plane per wave): gate gi -> nt = p + 8*gi
  const int hls = isHi ? 0 : 1;
  s8v Fih[6];    // [gi*2+kt]
  s8v Fhh[12];   // [gi*4+kt]
  #pragma unroll
  for (int gi = 0; gi < 3; ++gi) {
    int nt = p + 8 * gi;
    #pragma unroll
    for (int kt = 0; kt < 2; ++kt)
      Fih[gi * 2 + kt] = *(const s8v*)&fih[((long)((nt * 2 + kt) * 2 + hls)) * 512 + l * 8];
    #pragma unroll
    for (int kt = 0; kt < 4; ++kt)
      Fhh[gi * 4 + kt] = *(const s8v*)&fhh[((long)((nt * 4 + kt) * 2 + hls)) * 512 + l * 8];
  }

  // x staging assignment (lo-waves): sid in [0,512): plane = sid>>8, q = sid&255
  const int sid = (wv - 8) * 64 + l;            // valid for lo-waves
  const int spl = sid >> 8, sq = sid & 255;
  const int srow = sq >> 4, sc8 = sq & 15;
  const ushort* xsrc = spl ? xlo : xhi;

  // prologue: stage x(t0) into xs[0]
  if (!isHi) {
    ushort4 v = *(const ushort4*)&xsrc[((b0 + srow) * 128 + t0) * 64 + sc8 * 4];
    *(ushort4*)&xs[0][spl][srow][sc8 * 4] = v;
  }
  __syncthreads();

  int pp = 0;
  for (int s = 0; s < tc; ++s, pp ^= 1) {
    const int havenext = (s + 1 < tc);
    ushort4 xr;
    if (!isHi && havenext)
      xr = *(const ushort4*)&xsrc[((b0 + srow) * 128 + (t0 + s + 1)) * 64 + sc8 * 4];

    f4v ar = {0.f, 0.f, 0.f, 0.f}, az = ar, anx = ar, anh = ar;
    if (isHi) {
      #pragma unroll
      for (int kt = 0; kt < 4; ++kt) {
        int ba = lr * 256 + ((kt * 64 + lg * 16) ^ ((lr & 7) << 4));
        s8v Ah = *(const s8v*)((const char*)hh_[pp] + ba);
        s8v Al = *(const s8v*)((const char*)hl_[pp] + ba);
        MF(Fhh[0 * 4 + kt], Ah, ar);
        MF(Fhh[1 * 4 + kt], Ah, az);
        MF(Fhh[2 * 4 + kt], Ah, anh);
        MF(Fhh[0 * 4 + kt], Al, ar);
        MF(Fhh[1 * 4 + kt], Al, az);
        MF(Fhh[2 * 4 + kt], Al, anh);
      }
      #pragma unroll
      for (int kt = 0; kt < 2; ++kt) {
        s8v xh = *(const s8v*)&xs[pp][0][lr][kt * 32 + lg * 8];
        s8v xl = *(const s8v*)&xs[pp][1][lr][kt * 32 + lg * 8];
        MF(Fih[0 * 2 + kt], xh, ar);
        MF(Fih[1 * 2 + kt], xh, az);
        MF(Fih[2 * 2 + kt], xh, anx);
        MF(Fih[0 * 2 + kt], xl, ar);
        MF(Fih[1 * 2 + kt], xl, az);
        MF(Fih[2 * 2 + kt], xl, anx);
      }
    } else {
      #pragma unroll
      for (int kt = 0; kt < 4; ++kt) {
        int ba = lr * 256 + ((kt * 64 + lg * 16) ^ ((lr & 7) << 4));
        s8v Ah = *(const s8v*)((const char*)hh_[pp] + ba);
        MF(Fhh[0 * 4 + kt], Ah, ar);
        MF(Fhh[1 * 4 + kt], Ah, az);
        MF(Fhh[2 * 4 + kt], Ah, anh);
      }
      #pragma unroll
      for (int kt = 0; kt < 2; ++kt) {
        s8v xh = *(const s8v*)&xs[pp][0][lr][kt * 32 + lg * 8];
        MF(Fih[0 * 2 + kt], xh, ar);
        MF(Fih[1 * 2 + kt], xh, az);
        MF(Fih[2 * 2 + kt], xh, anx);
      }
      // dump partials (swizzled, conflict-free)
      ((f4v*)pd[p][0])[lsw] = ar;
      ((f4v*)pd[p][1])[lsw] = az;
      ((f4v*)pd[p][2])[lsw] = anx;
      ((f4v*)pd[p][3])[lsw] = anh;
    }
    __syncthreads();

    if (isHi) {
      ar  += ((const f4v*)pd[p][0])[lsw];
      az  += ((const f4v*)pd[p][1])[lsw];
      anx += ((const f4v*)pd[p][2])[lsw];
      anh += ((const f4v*)pd[p][3])[lsw];
      ushort4 oh = *(const ushort4*)((const char*)hh_[pp] + hb);
      ushort4 ol = *(const ushort4*)((const char*)hl_[pp] + hb);
      f4v vbr = *(const f4v*)&bb[u0];
      f4v vbz = *(const f4v*)&bb[128 + u0];
      f4v vbx = *(const f4v*)&bb[256 + u0];
      f4v vbh = *(const f4v*)&bb[384 + u0];
      const ushort* ohp = (const ushort*)&oh;
      const ushort* olp = (const ushort*)&ol;
      ushort nh_[4], nl_[4];
      #pragma unroll
      for (int j = 0; j < 4; ++j) {
        float hold = bf2f(ohp[j]) + bf2f(olp[j]);
        float rg = sigm(ar[j] + vbr[j]);
        float zg = sigm(az[j] + vbz[j]);
        float ng = tanh_safe(anx[j] + vbx[j] + rg * (anh[j] + vbh[j]));
        float hn = (1.f - zg) * ng + zg * hold;
        ushort hbf = f2bf(hn);
        nh_[j] = hbf; nl_[j] = f2bf(hn - bf2f(hbf));
      }
      ushort4 wh = make_ushort4(nh_[0], nh_[1], nh_[2], nh_[3]);
      ushort4 wl = make_ushort4(nl_[0], nl_[1], nl_[2], nl_[3]);
      *(ushort4*)((char*)hh_[pp ^ 1] + hb) = wh;
      *(ushort4*)((char*)hl_[pp ^ 1] + hb) = wl;
      long so = ((long)s * 4096 + b0 + lr) * 128 + u0;
      *(ushort4*)&s_hi[so] = wh;
      *(ushort4*)&s_lo[so] = wl;
    } else if (havenext) {
      *(ushort4*)&xs[pp ^ 1][spl][srow][sc8 * 4] = xr;
    }
    __syncthreads();
  }
  if (isHi) {
    *(ushort4*)&c_hi[(b0 + lr) * 128 + u0] = *(const ushort4*)((const char*)hh_[pp] + hb);
    *(ushort4*)&c_lo[(b0 + lr) * 128 + u0] = *(const ushort4*)((const char*)hl_[pp] + hb);
  }
}

// ---------- layer 1: h0 input staged global->reg->swizzled LDS (R5 form) ----------
__global__ void __attribute__((amdgpu_flat_work_group_size(512, 512),
                               amdgpu_waves_per_eu(2, 2)))
rec_l1(const ushort* __restrict__ s_hi, const ushort* __restrict__ s_lo,
       const ushort* __restrict__ fih, const ushort* __restrict__ fhh,
       const float* __restrict__ bi, const float* __restrict__ bh,
       ushort* __restrict__ c_hi, ushort* __restrict__ c_lo,
       float* __restrict__ h1f, int tc, int first, int last)
{
  __shared__ __align__(16) ushort hh_[2][2048], hl_[2][2048];  // h1 state (swizzled)
  __shared__ __align__(16) ushort gh_[2][2048], gl_[2][2048];  // staged h0 (swizzled)
  __shared__ __align__(16) float bb[512];
  const int tid = threadIdx.x;
  const int l = tid & 63, wv = tid >> 6;
  const int lr = l & 15, lg = l >> 4;
  const long b0 = (long)blockIdx.x * 16;

  if (tid < 128) {
    bb[tid]       = bi[tid] + bh[tid];
    bb[128 + tid] = bi[128 + tid] + bh[128 + tid];
    bb[256 + tid] = bi[256 + tid];
    bb[384 + tid] = bh[256 + tid];
  }
  const int u0 = (wv << 4) + (lg << 2);
  const int hb = lr * 256 + ((u0 << 1) ^ ((lr & 7) << 4));
  if (first) {
    *(ushort4*)((char*)hh_[0] + hb) = make_ushort4(0, 0, 0, 0);
    *(ushort4*)((char*)hl_[0] + hb) = make_ushort4(0, 0, 0, 0);
  } else {
    *(ushort4*)((char*)hh_[0] + hb) = *(const ushort4*)&c_hi[(b0 + lr) * 128 + u0];
    *(ushort4*)((char*)hl_[0] + hb) = *(const ushort4*)&c_lo[(b0 + lr) * 128 + u0];
  }

  const int stid = tid & 255;
  const int srow = stid >> 4, sc16 = stid & 15;
  const int sdst = srow * 256 + ((sc16 * 16) ^ ((srow & 7) << 4));
  const ushort* ssel = (tid < 256) ? s_hi : s_lo;
  ushort* dsel = (tid < 256) ? &gh_[0][0] : &gl_[0][0];

  s8v Ba[24], Bb[24];
  #pragma unroll
  for (int gi = 0; gi < 3; ++gi) {
    int nt = wv + 8 * gi;
    #pragma unroll
    for (int kt = 0; kt < 4; ++kt)
      #pragma unroll
      for (int hl = 0; hl < 2; ++hl) {
        Ba[(gi * 4 + kt) * 2 + hl] = *(const s8v*)&fih[((long)((nt * 4 + kt) * 2 + hl)) * 512 + l * 8];
        Bb[(gi * 4 + kt) * 2 + hl] = *(const s8v*)&fhh[((long)((nt * 4 + kt) * 2 + hl)) * 512 + l * 8];
      }
  }
  {
    s8v v = *(const s8v*)&ssel[((long)0 * 4096 + b0 + srow) * 128 + sc16 * 8];
    *(s8v*)((char*)(dsel + 0 * 2048) + sdst) = v;
  }
  __syncthreads();

  int pp = 0;
  for (int tl = 0; tl < tc; ++tl, pp ^= 1) {
    s8v sreg;
    const int havenext = (tl + 1 < tc);
    if (havenext)
      sreg = *(const s8v*)&ssel[((long)(tl + 1) * 4096 + b0 + srow) * 128 + sc16 * 8];

    f4v ar = {0.f, 0.f, 0.f, 0.f}, az = ar, anx = ar, anh = ar;
    #pragma unroll
    for (int kt = 0; kt < 4; ++kt) {
      int ba = lr * 256 + ((kt * 64 + lg * 16) ^ ((lr & 7) << 4));
      s8v Hh = *(const s8v*)((const char*)hh_[pp] + ba);
      s8v Hl = *(const s8v*)((const char*)hl_[pp] + ba);
      s8v Gh = *(const s8v*)((const char*)gh_[pp] + ba);
      s8v Gl = *(const s8v*)((const char*)gl_[pp] + ba);
      MF(Bb[(0 * 4 + kt) * 2 + 0], Hh, ar);
      MF(Ba[(0 * 4 + kt) * 2 + 0], Gh, ar);
      MF(Bb[(1 * 4 + kt) * 2 + 0], Hh, az);
      MF(Ba[(1 * 4 + kt) * 2 + 0], Gh, az);
      MF(Bb[(2 * 4 + kt) * 2 + 0], Hh, anh);
      MF(Ba[(2 * 4 + kt) * 2 + 0], Gh, anx);
      MF(Bb[(0 * 4 + kt) * 2 + 1], Hh, ar);
      MF(Ba[(0 * 4 + kt) * 2 + 1], Gh, ar);
      MF(Bb[(1 * 4 + kt) * 2 + 1], Hh, az);
      MF(Ba[(1 * 4 + kt) * 2 + 1], Gh, az);
      MF(Bb[(2 * 4 + kt) * 2 + 1], Hh, anh);
      MF(Ba[(2 * 4 + kt) * 2 + 1], Gh, anx);
      MF(Bb[(0 * 4 + kt) * 2 + 0], Hl, ar);
      MF(Ba[(0 * 4 + kt) * 2 + 0], Gl, ar);
      MF(Bb[(1 * 4 + kt) * 2 + 0], Hl, az);
      MF(Ba[(1 * 4 + kt) * 2 + 0], Gl, az);
      MF(Bb[(2 * 4 + kt) * 2 + 0], Hl, anh);
      MF(Ba[(2 * 4 + kt) * 2 + 0], Gl, anx);
    }
    {
      ushort4 oh = *(const ushort4*)((const char*)hh_[pp] + hb);
      ushort4 ol = *(const ushort4*)((const char*)hl_[pp] + hb);
      f4v vbr = *(const f4v*)&bb[u0];
      f4v vbz = *(const f4v*)&bb[128 + u0];
      f4v vbx = *(const f4v*)&bb[256 + u0];
      f4v vbh = *(const f4v*)&bb[384 + u0];
      const ushort* ohp = (const ushort*)&oh;
      const ushort* olp = (const ushort*)&ol;
      ushort nh_[4], nl_[4];
      #pragma unroll
      for (int j = 0; j < 4; ++j) {
        float hold = bf2f(ohp[j]) + bf2f(olp[j]);
        float rg = sigm(ar[j] + vbr[j]);
        float zg = sigm(az[j] + vbz[j]);
        float ng = tanh_safe(anx[j] + vbx[j] + rg * (anh[j] + vbh[j]));
        float hn = (1.f - zg) * ng + zg * hold;
        ushort hbf = f2bf(hn);
        nh_[j] = hbf; nl_[j] = f2bf(hn - bf2f(hbf));
      }
      *(ushort4*)((char*)hh_[pp ^ 1] + hb) = make_ushort4(nh_[0], nh_[1], nh_[2], nh_[3]);
      *(ushort4*)((char*)hl_[pp ^ 1] + hb) = make_ushort4(nl_[0], nl_[1], nl_[2], nl_[3]);
    }
    if (havenext)
      *(s8v*)((char*)(dsel + (size_t)(pp ^ 1) * 2048) + sdst) = sreg;
    __syncthreads();
  }
  {
    ushort4 fh = *(const ushort4*)((const char*)hh_[pp] + hb);
    ushort4 fl = *(const ushort4*)((const char*)hl_[pp] + hb);
    *(ushort4*)&c_hi[(b0 + lr) * 128 + u0] = fh;
    *(ushort4*)&c_lo[(b0 + lr) * 128 + u0] = fl;
    if (last) {
      const ushort* fhp = (const ushort*)&fh;
      const ushort* flp = (const ushort*)&fl;
      float4 o;
      o.x = bf2f(fhp[0]) + bf2f(flp[0]);
      o.y = bf2f(fhp[1]) + bf2f(flp[1]);
      o.z = bf2f(fhp[2]) + bf2f(flp[2]);
      o.w = bf2f(fhp[3]) + bf2f(flp[3]);
      *(float4*)&h1f[(b0 + lr) * 128 + u0] = o;
    }
  }
}

// ---------- head: relu(h1 @ w1^T + b1) @ w2^T + b2 ----------
__global__ __launch_bounds__(512) void head_k(
    const float* __restrict__ h1f, const float* __restrict__ w1,
    const float* __restrict__ b1, const float* __restrict__ w2,
    const float* __restrict__ b2, float* __restrict__ out)
{
  __shared__ float hrow[16][132];
  __shared__ float w1s[64][132];
  __shared__ float hid[16][68];
  const int tid = threadIdx.x;
  const long b0 = (long)blockIdx.x * 16;
  for (int i = tid; i < 64 * 128; i += 512) w1s[i >> 7][i & 127] = w1[i];
  {
    int rr = tid >> 5, k4 = (tid & 31) * 4;
    *(float4*)&hrow[rr][k4] = *(const float4*)&h1f[(b0 + rr) * 128 + k4];
  }
  __syncthreads();
  {
    int r = tid & 15, fu = tid >> 4;
    float a0 = 0.f, a1 = 0.f;
    for (int k4 = 0; k4 < 32; ++k4) {
      float4 hv = *(const float4*)&hrow[r][k4 * 4];
      float4 wa = *(const float4*)&w1s[fu][k4 * 4];
      float4 wb = *(const float4*)&w1s[fu + 32][k4 * 4];
      a0 += dot4(wa, hv);
      a1 += dot4(wb, hv);
    }
    a0 += b1[fu]; a1 += b1[fu + 32];
    hid[r][fu]      = fmaxf(a0, 0.f);
    hid[r][fu + 32] = fmaxf(a1, 0.f);
  }
  __syncthreads();
  if (tid < 176) {
    int rr = tid / 11, c = tid - rr * 11;
    float acc = b2[c];
    for (int k = 0; k < 64; ++k) acc = fmaf(w2[c * 64 + k], hid[rr][k], acc);
    out[(b0 + rr) * 11 + c] = acc;
  }
}

extern "C" void kernel_launch(void* const* d_in, const int* in_sizes, int n_in,
                              void* d_out, int out_size, void* d_ws, size_t ws_size,
                              hipStream_t stream) {
  (void)in_sizes; (void)n_in; (void)out_size;
  const float* x    = (const float*)d_in[0];
  const float* wih0 = (const float*)d_in[1];
  const float* whh0 = (const float*)d_in[2];
  const float* bih0 = (const float*)d_in[3];
  const float* bhh0 = (const float*)d_in[4];
  const float* wih1 = (const float*)d_in[5];
  const float* whh1 = (const float*)d_in[6];
  const float* bih1 = (const float*)d_in[7];
  const float* bhh1 = (const float*)d_in[8];
  const float* w1   = (const float*)d_in[9];
  const float* b1   = (const float*)d_in[10];
  const float* w2   = (const float*)d_in[11];
  const float* b2   = (const float*)d_in[12];

  char* wsb = (char*)d_ws;
  size_t o = 0;
  ushort* fih0 = (ushort*)(wsb + o); o += 98304;
  ushort* fhh0 = (ushort*)(wsb + o); o += 196608;
  ushort* fih1 = (ushort*)(wsb + o); o += 196608;
  ushort* fhh1 = (ushort*)(wsb + o); o += 196608;
  ushort* xhi  = (ushort*)(wsb + o); o += 67108864ULL;
  ushort* xlo  = (ushort*)(wsb + o); o += 67108864ULL;
  ushort* hc0h = (ushort*)(wsb + o); o += 1048576;
  ushort* hc0l = (ushort*)(wsb + o); o += 1048576;
  ushort* hc1h = (ushort*)(wsb + o); o += 1048576;
  ushort* hc1l = (ushort*)(wsb + o); o += 1048576;
  float*  h1f  = (float*)(wsb + o);  o += 2097152;

  long rem = (long)ws_size - (long)o;
  long tcmax = rem / (2 * 1048576L);
  int Tc = tcmax > 128 ? 128 : (int)tcmax;
  if (Tc < 1) return;  // ws too small
  ushort* sh = (ushort*)(wsb + o);
  ushort* sl = sh + (long)Tc * 524288;

  hipLaunchKernelGGL(conv_x, dim3(32768), dim3(256), 0, stream, x, xhi, xlo, 8388608);
  hipLaunchKernelGGL(pack_fr, dim3(192), dim3(256), 0, stream, wih0, fih0, 63, 2, 49152);
  hipLaunchKernelGGL(pack_fr, dim3(384), dim3(256), 0, stream, whh0, fhh0, 128, 4, 98304);
  hipLaunchKernelGGL(pack_fr, dim3(384), dim3(256), 0, stream, wih1, fih1, 128, 4, 98304);
  hipLaunchKernelGGL(pack_fr, dim3(384), dim3(256), 0, stream, whh1, fhh1, 128, 4, 98304);

  for (int t0 = 0; t0 < 128; t0 += Tc) {
    int tc = (128 - t0) < Tc ? (128 - t0) : Tc;
    hipLaunchKernelGGL(rec_l0, dim3(256), dim3(1024), 0, stream,
                       xhi, xlo, fih0, fhh0, bih0, bhh0, sh, sl, hc0h, hc0l,
                       t0, tc, (int)(t0 == 0));
    hipLaunchKernelGGL(rec_l1, dim3(256), dim3(512), 0, stream,
                       sh, sl, fih1, fhh1, bih1, bhh1, hc1h, hc1l, h1f,
                       tc, (int)(t0 == 0), (int)(t0 + tc == 128));
  }
  hipLaunchKernelGGL(head_k, dim3(256), dim3(512), 0, stream,
                     h1f, w1, b1, w2, b2, (float*)d_out);
}

// Round 9
// 922.392 us; speedup vs baseline: 1.0931x; 1.0931x over previous
//
#include <hip/hip_runtime.h>
#include <hip/hip_bf16.h>

typedef __attribute__((ext_vector_type(8))) short s8v;   // 8 bf16 = 4 VGPR
typedef __attribute__((ext_vector_type(4))) float f4v;   // MFMA acc

// A = weight frag, B = data frag  ->  C[m=unit][n=batch-row]
#define MF(A, B, C) C = __builtin_amdgcn_mfma_f32_16x16x32_bf16((A), (B), (C), 0, 0, 0)

__device__ __forceinline__ ushort f2bf(float f) {
  unsigned u = __float_as_uint(f);
  u += 0x7FFF + ((u >> 16) & 1);        // RNE (finite inputs only)
  return (ushort)(u >> 16);
}
__device__ __forceinline__ float bf2f(ushort h) {
  return __uint_as_float(((unsigned)h) << 16);
}
__device__ __forceinline__ float sigm(float p) { return 1.f / (1.f + __expf(-p)); }
__device__ __forceinline__ float tanh_safe(float a) {
  float t = __expf(-2.f * fabsf(a));
  float ng = (1.f - t) / (1.f + t);
  return a < 0.f ? -ng : ng;
}
__device__ __forceinline__ float dot4(float4 a, float4 b) {
  return fmaf(a.x, b.x, fmaf(a.y, b.y, fmaf(a.z, b.z, a.w * b.w)));
}

// ---------- pre-pass: split x into bf16 hi/lo, pad K 63->64 ----------
__global__ void conv_x(const float* __restrict__ x, ushort* __restrict__ xhi,
                       ushort* __restrict__ xlo, int total) {
  int idx = blockIdx.x * 256 + threadIdx.x;
  if (idx >= total) return;                    // total = 4096*128*16
  int k4 = (idx & 15) * 4;
  long bt = idx >> 4;
  #pragma unroll
  for (int j = 0; j < 4; ++j) {
    int k = k4 + j;
    float v = (k < 63) ? x[bt * 63 + k] : 0.f;
    ushort hi = f2bf(v);
    xhi[bt * 64 + k] = hi;
    xlo[bt * 64 + k] = f2bf(v - bf2f(hi));
  }
}

// ---------- pre-pass: pack W [384][Kreal] into per-lane frag streams (hi/lo) ----------
// frag_id = (nt*KT + kt)*2 + hl ; lane l elem i supplies W[nt*16+(l&15)][kt*32+(l>>4)*8+i]
__global__ void pack_fr(const float* __restrict__ src, ushort* __restrict__ dst,
                        int Kreal, int KT, int total) {
  int idx = blockIdx.x * 256 + threadIdx.x;
  if (idx >= total) return;
  int i = idx & 7, l = (idx >> 3) & 63, hl = (idx >> 9) & 1;
  int rest = idx >> 10;
  int kt = rest % KT, nt = rest / KT;
  int g = nt * 16 + (l & 15);
  int k = kt * 32 + (l >> 4) * 8 + i;
  float v = (k < Kreal) ? src[g * Kreal + k] : 0.f;
  ushort hi = f2bf(v);
  dst[idx] = hl ? f2bf(v - bf2f(hi)) : hi;
}

// ---------- layer 0: 16 rows/block, 8 waves, deferred h-stream stores ----------
__global__ void __attribute__((amdgpu_flat_work_group_size(512, 512),
                               amdgpu_waves_per_eu(2, 2)))
rec_l0(const ushort* __restrict__ xhi, const ushort* __restrict__ xlo,
       const ushort* __restrict__ fih, const ushort* __restrict__ fhh,
       const float* __restrict__ bi, const float* __restrict__ bh,
       ushort* __restrict__ s_hi, ushort* __restrict__ s_lo,
       ushort* __restrict__ c_hi, ushort* __restrict__ c_lo,
       int t0, int tc, int first)
{
  __shared__ __align__(16) ushort hh_[2][2048], hl_[2][2048];  // swizzled h state
  __shared__ __align__(16) float bb[512];
  const int tid = threadIdx.x;
  const int l = tid & 63, wv = tid >> 6;
  const int lr = l & 15, lg = l >> 4;
  const long b0 = (long)blockIdx.x * 16;

  if (tid < 128) {
    bb[tid]       = bi[tid] + bh[tid];
    bb[128 + tid] = bi[128 + tid] + bh[128 + tid];
    bb[256 + tid] = bi[256 + tid];
    bb[384 + tid] = bh[256 + tid];
  }
  const int u0 = (wv << 4) + (lg << 2);
  const int hb = lr * 256 + ((u0 << 1) ^ ((lr & 7) << 4));
  if (first) {
    *(ushort4*)((char*)hh_[0] + hb) = make_ushort4(0, 0, 0, 0);
    *(ushort4*)((char*)hl_[0] + hb) = make_ushort4(0, 0, 0, 0);
  } else {
    *(ushort4*)((char*)hh_[0] + hb) = *(const ushort4*)&c_hi[(b0 + lr) * 128 + u0];
    *(ushort4*)((char*)hl_[0] + hb) = *(const ushort4*)&c_lo[(b0 + lr) * 128 + u0];
  }

  // parked weight frags: gate gi -> nt = wv + 8*gi
  s8v Ba[12];   // ih [(gi*2+kt)*2+hl]
  s8v Bb[24];   // hh [(gi*4+kt)*2+hl]
  #pragma unroll
  for (int gi = 0; gi < 3; ++gi) {
    int nt = wv + 8 * gi;
    #pragma unroll
    for (int kt = 0; kt < 2; ++kt)
      #pragma unroll
      for (int hl = 0; hl < 2; ++hl)
        Ba[(gi * 2 + kt) * 2 + hl] = *(const s8v*)&fih[((long)((nt * 2 + kt) * 2 + hl)) * 512 + l * 8];
    #pragma unroll
    for (int kt = 0; kt < 4; ++kt)
      #pragma unroll
      for (int hl = 0; hl < 2; ++hl)
        Bb[(gi * 4 + kt) * 2 + hl] = *(const s8v*)&fhh[((long)((nt * 4 + kt) * 2 + hl)) * 512 + l * 8];
  }

  // x register double-buffer (B-frags: lane lr=row, k=(lg*8..)+kt*32)
  s8v xch[2], xcl[2], xnh[2], xnl[2];
  {
    long xo = ((b0 + lr) * 128 + t0) * 64 + lg * 8;
    xch[0] = *(const s8v*)&xhi[xo]; xch[1] = *(const s8v*)&xhi[xo + 32];
    xcl[0] = *(const s8v*)&xlo[xo]; xcl[1] = *(const s8v*)&xlo[xo + 32];
  }
  __syncthreads();

  const long sbase = (b0 + lr) * 128 + u0;   // h-stream slot (stride 524288/step)
  ushort4 st_h, st_l;                        // deferred-store payload

  int pp = 0;
  for (int s = 0; s < tc; ++s, pp ^= 1) {
    // deferred global store of step s-1's h (gets a full step of cover)
    if (s > 0) {
      *(ushort4*)&s_hi[sbase + (long)(s - 1) * 524288] = st_h;
      *(ushort4*)&s_lo[sbase + (long)(s - 1) * 524288] = st_l;
    }
    if (s + 1 < tc) {
      long xo = ((b0 + lr) * 128 + (t0 + s + 1)) * 64 + lg * 8;
      xnh[0] = *(const s8v*)&xhi[xo]; xnh[1] = *(const s8v*)&xhi[xo + 32];
      xnl[0] = *(const s8v*)&xlo[xo]; xnl[1] = *(const s8v*)&xlo[xo + 32];
    }
    f4v ar = {0.f, 0.f, 0.f, 0.f}, az = ar, anx = ar, anh = ar;
    #pragma unroll
    for (int kt = 0; kt < 4; ++kt) {
      int ba = lr * 256 + ((kt * 64 + lg * 16) ^ ((lr & 7) << 4));
      s8v Ah = *(const s8v*)((const char*)hh_[pp] + ba);
      s8v Al = *(const s8v*)((const char*)hl_[pp] + ba);
      MF(Bb[(0 * 4 + kt) * 2 + 0], Ah, ar);
      MF(Bb[(1 * 4 + kt) * 2 + 0], Ah, az);
      MF(Bb[(2 * 4 + kt) * 2 + 0], Ah, anh);
      MF(Bb[(0 * 4 + kt) * 2 + 1], Ah, ar);
      MF(Bb[(1 * 4 + kt) * 2 + 1], Ah, az);
      MF(Bb[(2 * 4 + kt) * 2 + 1], Ah, anh);
      MF(Bb[(0 * 4 + kt) * 2 + 0], Al, ar);
      MF(Bb[(1 * 4 + kt) * 2 + 0], Al, az);
      MF(Bb[(2 * 4 + kt) * 2 + 0], Al, anh);
    }
    #pragma unroll
    for (int kt = 0; kt < 2; ++kt) {
      MF(Ba[(0 * 2 + kt) * 2 + 0], xch[kt], ar);
      MF(Ba[(1 * 2 + kt) * 2 + 0], xch[kt], az);
      MF(Ba[(2 * 2 + kt) * 2 + 0], xch[kt], anx);
      MF(Ba[(0 * 2 + kt) * 2 + 1], xch[kt], ar);
      MF(Ba[(1 * 2 + kt) * 2 + 1], xch[kt], az);
      MF(Ba[(2 * 2 + kt) * 2 + 1], xch[kt], anx);
      MF(Ba[(0 * 2 + kt) * 2 + 0], xcl[kt], ar);
      MF(Ba[(1 * 2 + kt) * 2 + 0], xcl[kt], az);
      MF(Ba[(2 * 2 + kt) * 2 + 0], xcl[kt], anx);
    }
    // in-register pointwise: row lr, units u0..u0+3
    {
      ushort4 oh = *(const ushort4*)((const char*)hh_[pp] + hb);
      ushort4 ol = *(const ushort4*)((const char*)hl_[pp] + hb);
      f4v vbr = *(const f4v*)&bb[u0];
      f4v vbz = *(const f4v*)&bb[128 + u0];
      f4v vbx = *(const f4v*)&bb[256 + u0];
      f4v vbh = *(const f4v*)&bb[384 + u0];
      const ushort* ohp = (const ushort*)&oh;
      const ushort* olp = (const ushort*)&ol;
      ushort nh_[4], nl_[4];
      #pragma unroll
      for (int j = 0; j < 4; ++j) {
        float hold = bf2f(ohp[j]) + bf2f(olp[j]);
        float rg = sigm(ar[j] + vbr[j]);
        float zg = sigm(az[j] + vbz[j]);
        float ng = tanh_safe(anx[j] + vbx[j] + rg * (anh[j] + vbh[j]));
        float hn = (1.f - zg) * ng + zg * hold;
        ushort hbf = f2bf(hn);
        nh_[j] = hbf; nl_[j] = f2bf(hn - bf2f(hbf));
      }
      ushort4 wh = make_ushort4(nh_[0], nh_[1], nh_[2], nh_[3]);
      ushort4 wl = make_ushort4(nl_[0], nl_[1], nl_[2], nl_[3]);
      *(ushort4*)((char*)hh_[pp ^ 1] + hb) = wh;
      *(ushort4*)((char*)hl_[pp ^ 1] + hb) = wl;
      st_h = wh; st_l = wl;                   // store deferred to next iteration
    }
    xch[0] = xnh[0]; xch[1] = xnh[1]; xcl[0] = xnl[0]; xcl[1] = xnl[1];
    __syncthreads();
  }
  // flush last step's h-stream slot + carry state
  *(ushort4*)&s_hi[sbase + (long)(tc - 1) * 524288] = st_h;
  *(ushort4*)&s_lo[sbase + (long)(tc - 1) * 524288] = st_l;
  *(ushort4*)&c_hi[(b0 + lr) * 128 + u0] = *(const ushort4*)((const char*)hh_[pp] + hb);
  *(ushort4*)&c_lo[(b0 + lr) * 128 + u0] = *(const ushort4*)((const char*)hl_[pp] + hb);
}

// ---------- layer 1: h0 input read DIRECTLY from global (no LDS staging) ----------
__global__ void __attribute__((amdgpu_flat_work_group_size(512, 512),
                               amdgpu_waves_per_eu(2, 2)))
rec_l1(const ushort* __restrict__ s_hi, const ushort* __restrict__ s_lo,
       const ushort* __restrict__ fih, const ushort* __restrict__ fhh,
       const float* __restrict__ bi, const float* __restrict__ bh,
       ushort* __restrict__ c_hi, ushort* __restrict__ c_lo,
       float* __restrict__ h1f, int tc, int first, int last)
{
  __shared__ __align__(16) ushort hh_[2][2048], hl_[2][2048];  // h1 state (swizzled)
  __shared__ __align__(16) float bb[512];
  const int tid = threadIdx.x;
  const int l = tid & 63, wv = tid >> 6;
  const int lr = l & 15, lg = l >> 4;
  const long b0 = (long)blockIdx.x * 16;

  if (tid < 128) {
    bb[tid]       = bi[tid] + bh[tid];
    bb[128 + tid] = bi[128 + tid] + bh[128 + tid];
    bb[256 + tid] = bi[256 + tid];
    bb[384 + tid] = bh[256 + tid];
  }
  const int u0 = (wv << 4) + (lg << 2);
  const int hb = lr * 256 + ((u0 << 1) ^ ((lr & 7) << 4));
  if (first) {
    *(ushort4*)((char*)hh_[0] + hb) = make_ushort4(0, 0, 0, 0);
    *(ushort4*)((char*)hl_[0] + hb) = make_ushort4(0, 0, 0, 0);
  } else {
    *(ushort4*)((char*)hh_[0] + hb) = *(const ushort4*)&c_hi[(b0 + lr) * 128 + u0];
    *(ushort4*)((char*)hl_[0] + hb) = *(const ushort4*)&c_lo[(b0 + lr) * 128 + u0];
  }

  // parked weight frags
  s8v Ba[24], Bb[24];
  #pragma unroll
  for (int gi = 0; gi < 3; ++gi) {
    int nt = wv + 8 * gi;
    #pragma unroll
    for (int kt = 0; kt < 4; ++kt)
      #pragma unroll
      for (int hl = 0; hl < 2; ++hl) {
        Ba[(gi * 4 + kt) * 2 + hl] = *(const s8v*)&fih[((long)((nt * 4 + kt) * 2 + hl)) * 512 + l * 8];
        Bb[(gi * 4 + kt) * 2 + hl] = *(const s8v*)&fhh[((long)((nt * 4 + kt) * 2 + hl)) * 512 + l * 8];
      }
  }
  __syncthreads();

  // G B-frag source: lane (lr,lg) reads contiguous 16B at [row=lr][kt*32+lg*8]
  const long gbase0 = (b0 + lr) * 128 + lg * 8;

  int pp = 0;
  for (int tl = 0; tl < tc; ++tl, pp ^= 1) {
    const long gb = (long)tl * 524288 + gbase0;
    s8v Gh[4], Gl[4];
    // first half of G loads; covered by H-section MFMAs below
    Gh[0] = *(const s8v*)&s_hi[gb];        Gh[1] = *(const s8v*)&s_hi[gb + 32];
    Gl[0] = *(const s8v*)&s_lo[gb];        Gl[1] = *(const s8v*)&s_lo[gb + 32];

    f4v ar = {0.f, 0.f, 0.f, 0.f}, az = ar, anx = ar, anh = ar;
    // H (h1 recurrent) section
    #pragma unroll
    for (int kt = 0; kt < 4; ++kt) {
      int ba = lr * 256 + ((kt * 64 + lg * 16) ^ ((lr & 7) << 4));
      s8v Hh = *(const s8v*)((const char*)hh_[pp] + ba);
      s8v Hl = *(const s8v*)((const char*)hl_[pp] + ba);
      MF(Bb[(0 * 4 + kt) * 2 + 0], Hh, ar);
      MF(Bb[(1 * 4 + kt) * 2 + 0], Hh, az);
      MF(Bb[(2 * 4 + kt) * 2 + 0], Hh, anh);
      MF(Bb[(0 * 4 + kt) * 2 + 1], Hh, ar);
      MF(Bb[(1 * 4 + kt) * 2 + 1], Hh, az);
      MF(Bb[(2 * 4 + kt) * 2 + 1], Hh, anh);
      MF(Bb[(0 * 4 + kt) * 2 + 0], Hl, ar);
      MF(Bb[(1 * 4 + kt) * 2 + 0], Hl, az);
      MF(Bb[(2 * 4 + kt) * 2 + 0], Hl, anh);
      if (kt == 1) {  // second half of G loads, still with cover
        Gh[2] = *(const s8v*)&s_hi[gb + 64];  Gh[3] = *(const s8v*)&s_hi[gb + 96];
        Gl[2] = *(const s8v*)&s_lo[gb + 64];  Gl[3] = *(const s8v*)&s_lo[gb + 96];
      }
    }
    // G (h0 input) section
    #pragma unroll
    for (int kt = 0; kt < 4; ++kt) {
      MF(Ba[(0 * 4 + kt) * 2 + 0], Gh[kt], ar);
      MF(Ba[(1 * 4 + kt) * 2 + 0], Gh[kt], az);
      MF(Ba[(2 * 4 + kt) * 2 + 0], Gh[kt], anx);
      MF(Ba[(0 * 4 + kt) * 2 + 1], Gh[kt], ar);
      MF(Ba[(1 * 4 + kt) * 2 + 1], Gh[kt], az);
      MF(Ba[(2 * 4 + kt) * 2 + 1], Gh[kt], anx);
      MF(Ba[(0 * 4 + kt) * 2 + 0], Gl[kt], ar);
      MF(Ba[(1 * 4 + kt) * 2 + 0], Gl[kt], az);
      MF(Ba[(2 * 4 + kt) * 2 + 0], Gl[kt], anx);
    }
    {
      ushort4 oh = *(const ushort4*)((const char*)hh_[pp] + hb);
      ushort4 ol = *(const ushort4*)((const char*)hl_[pp] + hb);
      f4v vbr = *(const f4v*)&bb[u0];
      f4v vbz = *(const f4v*)&bb[128 + u0];
      f4v vbx = *(const f4v*)&bb[256 + u0];
      f4v vbh = *(const f4v*)&bb[384 + u0];
      const ushort* ohp = (const ushort*)&oh;
      const ushort* olp = (const ushort*)&ol;
      ushort nh_[4], nl_[4];
      #pragma unroll
      for (int j = 0; j < 4; ++j) {
        float hold = bf2f(ohp[j]) + bf2f(olp[j]);
        float rg = sigm(ar[j] + vbr[j]);
        float zg = sigm(az[j] + vbz[j]);
        float ng = tanh_safe(anx[j] + vbx[j] + rg * (anh[j] + vbh[j]));
        float hn = (1.f - zg) * ng + zg * hold;
        ushort hbf = f2bf(hn);
        nh_[j] = hbf; nl_[j] = f2bf(hn - bf2f(hbf));
      }
      *(ushort4*)((char*)hh_[pp ^ 1] + hb) = make_ushort4(nh_[0], nh_[1], nh_[2], nh_[3]);
      *(ushort4*)((char*)hl_[pp ^ 1] + hb) = make_ushort4(nl_[0], nl_[1], nl_[2], nl_[3]);
    }
    __syncthreads();
  }
  {
    ushort4 fh = *(const ushort4*)((const char*)hh_[pp] + hb);
    ushort4 fl = *(const ushort4*)((const char*)hl_[pp] + hb);
    *(ushort4*)&c_hi[(b0 + lr) * 128 + u0] = fh;
    *(ushort4*)&c_lo[(b0 + lr) * 128 + u0] = fl;
    if (last) {
      const ushort* fhp = (const ushort*)&fh;
      const ushort* flp = (const ushort*)&fl;
      float4 o;
      o.x = bf2f(fhp[0]) + bf2f(flp[0]);
      o.y = bf2f(fhp[1]) + bf2f(flp[1]);
      o.z = bf2f(fhp[2]) + bf2f(flp[2]);
      o.w = bf2f(fhp[3]) + bf2f(flp[3]);
      *(float4*)&h1f[(b0 + lr) * 128 + u0] = o;
    }
  }
}

// ---------- head: relu(h1 @ w1^T + b1) @ w2^T + b2 ----------
__global__ __launch_bounds__(512) void head_k(
    const float* __restrict__ h1f, const float* __restrict__ w1,
    const float* __restrict__ b1, const float* __restrict__ w2,
    const float* __restrict__ b2, float* __restrict__ out)
{
  __shared__ float hrow[16][132];
  __shared__ float w1s[64][132];
  __shared__ float hid[16][68];
  const int tid = threadIdx.x;
  const long b0 = (long)blockIdx.x * 16;
  for (int i = tid; i < 64 * 128; i += 512) w1s[i >> 7][i & 127] = w1[i];
  {
    int rr = tid >> 5, k4 = (tid & 31) * 4;
    *(float4*)&hrow[rr][k4] = *(const float4*)&h1f[(b0 + rr) * 128 + k4];
  }
  __syncthreads();
  {
    int r = tid & 15, fu = tid >> 4;
    float a0 = 0.f, a1 = 0.f;
    for (int k4 = 0; k4 < 32; ++k4) {
      float4 hv = *(const float4*)&hrow[r][k4 * 4];
      float4 wa = *(const float4*)&w1s[fu][k4 * 4];
      float4 wb = *(const float4*)&w1s[fu + 32][k4 * 4];
      a0 += dot4(wa, hv);
      a1 += dot4(wb, hv);
    }
    a0 += b1[fu]; a1 += b1[fu + 32];
    hid[r][fu]      = fmaxf(a0, 0.f);
    hid[r][fu + 32] = fmaxf(a1, 0.f);
  }
  __syncthreads();
  if (tid < 176) {
    int rr = tid / 11, c = tid - rr * 11;
    float acc = b2[c];
    for (int k = 0; k < 64; ++k) acc = fmaf(w2[c * 64 + k], hid[rr][k], acc);
    out[(b0 + rr) * 11 + c] = acc;
  }
}

extern "C" void kernel_launch(void* const* d_in, const int* in_sizes, int n_in,
                              void* d_out, int out_size, void* d_ws, size_t ws_size,
                              hipStream_t stream) {
  (void)in_sizes; (void)n_in; (void)out_size;
  const float* x    = (const float*)d_in[0];
  const float* wih0 = (const float*)d_in[1];
  const float* whh0 = (const float*)d_in[2];
  const float* bih0 = (const float*)d_in[3];
  const float* bhh0 = (const float*)d_in[4];
  const float* wih1 = (const float*)d_in[5];
  const float* whh1 = (const float*)d_in[6];
  const float* bih1 = (const float*)d_in[7];
  const float* bhh1 = (const float*)d_in[8];
  const float* w1   = (const float*)d_in[9];
  const float* b1   = (const float*)d_in[10];
  const float* w2   = (const float*)d_in[11];
  const float* b2   = (const float*)d_in[12];

  char* wsb = (char*)d_ws;
  size_t o = 0;
  ushort* fih0 = (ushort*)(wsb + o); o += 98304;
  ushort* fhh0 = (ushort*)(wsb + o); o += 196608;
  ushort* fih1 = (ushort*)(wsb + o); o += 196608;
  ushort* fhh1 = (ushort*)(wsb + o); o += 196608;
  ushort* xhi  = (ushort*)(wsb + o); o += 67108864ULL;
  ushort* xlo  = (ushort*)(wsb + o); o += 67108864ULL;
  ushort* hc0h = (ushort*)(wsb + o); o += 1048576;
  ushort* hc0l = (ushort*)(wsb + o); o += 1048576;
  ushort* hc1h = (ushort*)(wsb + o); o += 1048576;
  ushort* hc1l = (ushort*)(wsb + o); o += 1048576;
  float*  h1f  = (float*)(wsb + o);  o += 2097152;

  long rem = (long)ws_size - (long)o;
  long tcmax = rem / (2 * 1048576L);
  int Tc = tcmax > 128 ? 128 : (int)tcmax;
  if (Tc < 1) return;  // ws too small
  ushort* sh = (ushort*)(wsb + o);
  ushort* sl = sh + (long)Tc * 524288;

  hipLaunchKernelGGL(conv_x, dim3(32768), dim3(256), 0, stream, x, xhi, xlo, 8388608);
  hipLaunchKernelGGL(pack_fr, dim3(192), dim3(256), 0, stream, wih0, fih0, 63, 2, 49152);
  hipLaunchKernelGGL(pack_fr, dim3(384), dim3(256), 0, stream, whh0, fhh0, 128, 4, 98304);
  hipLaunchKernelGGL(pack_fr, dim3(384), dim3(256), 0, stream, wih1, fih1, 128, 4, 98304);
  hipLaunchKernelGGL(pack_fr, dim3(384), dim3(256), 0, stream, whh1, fhh1, 128, 4, 98304);

  for (int t0 = 0; t0 < 128; t0 += Tc) {
    int tc = (128 - t0) < Tc ? (128 - t0) : Tc;
    hipLaunchKernelGGL(rec_l0, dim3(256), dim3(512), 0, stream,
                       xhi, xlo, fih0, fhh0, bih0, bhh0, sh, sl, hc0h, hc0l,
                       t0, tc, (int)(t0 == 0));
    hipLaunchKernelGGL(rec_l1, dim3(256), dim3(512), 0, stream,
                       sh, sl, fih1, fhh1, bih1, bhh1, hc1h, hc1l, h1f,
                       tc, (int)(t0 == 0), (int)(t0 + tc == 128));
  }
  hipLaunchKernelGGL(head_k, dim3(256), dim3(512), 0, stream,
                     h1f, w1, b1, w2, b2, (float*)d_out);
}

// Round 10
// 750.710 us; speedup vs baseline: 1.3430x; 1.2287x over previous
//
#include <hip/hip_runtime.h>
#include <hip/hip_bf16.h>

typedef __attribute__((ext_vector_type(8))) short s8v;   // 8 bf16 = 4 VGPR
typedef __attribute__((ext_vector_type(4))) float f4v;   // MFMA acc

// A = weight frag, B = data frag  ->  C[m=unit][n=batch-row]
#define MF(A, B, C) C = __builtin_amdgcn_mfma_f32_16x16x32_bf16((A), (B), (C), 0, 0, 0)

__device__ __forceinline__ ushort f2bf(float f) {
  unsigned u = __float_as_uint(f);
  u += 0x7FFF + ((u >> 16) & 1);        // RNE (finite inputs only)
  return (ushort)(u >> 16);
}
__device__ __forceinline__ float bf2f(ushort h) {
  return __uint_as_float(((unsigned)h) << 16);
}
__device__ __forceinline__ float sigm(float p) { return 1.f / (1.f + __expf(-p)); }
__device__ __forceinline__ float tanh_safe(float a) {
  float t = __expf(-2.f * fabsf(a));
  float ng = (1.f - t) / (1.f + t);
  return a < 0.f ? -ng : ng;
}
__device__ __forceinline__ float dot4(float4 a, float4 b) {
  return fmaf(a.x, b.x, fmaf(a.y, b.y, fmaf(a.z, b.z, a.w * b.w)));
}

// ---------- pre-pass: pack W [384][Kreal] into per-lane frag streams (hi/lo) ----------
// frag_id = (nt*KT + kt)*2 + hl ; lane l elem i supplies W[nt*16+(l&15)][kt*32+(l>>4)*8+i]
__global__ void pack_fr(const float* __restrict__ src, ushort* __restrict__ dst,
                        int Kreal, int KT, int total) {
  int idx = blockIdx.x * 256 + threadIdx.x;
  if (idx >= total) return;
  int i = idx & 7, l = (idx >> 3) & 63, hl = (idx >> 9) & 1;
  int rest = idx >> 10;
  int kt = rest % KT, nt = rest / KT;
  int g = nt * 16 + (l & 15);
  int k = kt * 32 + (l >> 4) * 8 + i;
  float v = (k < Kreal) ? src[g * Kreal + k] : 0.f;
  ushort hi = f2bf(v);
  dst[idx] = hl ? f2bf(v - bf2f(hi)) : hi;
}

// ---------- layer 0: fp32 x loaded + split in-kernel; deferred h-stream stores ----------
__global__ void __attribute__((amdgpu_flat_work_group_size(512, 512),
                               amdgpu_waves_per_eu(2, 2)))
rec_l0(const float* __restrict__ x,
       const ushort* __restrict__ fih, const ushort* __restrict__ fhh,
       const float* __restrict__ bi, const float* __restrict__ bh,
       ushort* __restrict__ s_hi, ushort* __restrict__ s_lo,
       ushort* __restrict__ c_hi, ushort* __restrict__ c_lo,
       int t0, int tc, int first)
{
  __shared__ __align__(16) ushort hh_[2][2048], hl_[2][2048];  // swizzled h state
  __shared__ __align__(16) float bb[512];
  const int tid = threadIdx.x;
  const int l = tid & 63, wv = tid >> 6;
  const int lr = l & 15, lg = l >> 4;
  const long b0 = (long)blockIdx.x * 16;

  if (tid < 128) {
    bb[tid]       = bi[tid] + bh[tid];
    bb[128 + tid] = bi[128 + tid] + bh[128 + tid];
    bb[256 + tid] = bi[256 + tid];
    bb[384 + tid] = bh[256 + tid];
  }
  const int u0 = (wv << 4) + (lg << 2);
  const int hb = lr * 256 + ((u0 << 1) ^ ((lr & 7) << 4));
  if (first) {
    *(ushort4*)((char*)hh_[0] + hb) = make_ushort4(0, 0, 0, 0);
    *(ushort4*)((char*)hl_[0] + hb) = make_ushort4(0, 0, 0, 0);
  } else {
    *(ushort4*)((char*)hh_[0] + hb) = *(const ushort4*)&c_hi[(b0 + lr) * 128 + u0];
    *(ushort4*)((char*)hl_[0] + hb) = *(const ushort4*)&c_lo[(b0 + lr) * 128 + u0];
  }

  // parked weight frags: gate gi -> nt = wv + 8*gi
  s8v Ba[12];   // ih [(gi*2+kt)*2+hl]
  s8v Bb[24];   // hh [(gi*4+kt)*2+hl]
  #pragma unroll
  for (int gi = 0; gi < 3; ++gi) {
    int nt = wv + 8 * gi;
    #pragma unroll
    for (int kt = 0; kt < 2; ++kt)
      #pragma unroll
      for (int hl = 0; hl < 2; ++hl)
        Ba[(gi * 2 + kt) * 2 + hl] = *(const s8v*)&fih[((long)((nt * 2 + kt) * 2 + hl)) * 512 + l * 8];
    #pragma unroll
    for (int kt = 0; kt < 4; ++kt)
      #pragma unroll
      for (int hl = 0; hl < 2; ++hl)
        Bb[(gi * 4 + kt) * 2 + hl] = *(const s8v*)&fhh[((long)((nt * 4 + kt) * 2 + hl)) * 512 + l * 8];
  }

  // fp32 x loader: lane (lr,lg) needs k = kt*32 + lg*8 + i, row stride 63.
  // kt=1,lg=3 covers k=56..63; k=63 is the zero pad -> weight is zeroed, but we
  // must not read past row end: use overlapped load at k=59.
  float4 nf0, nf1, nf2, nf3;
  auto loadx = [&](int t) {
    long xr = ((b0 + lr) * 128 + t) * 63;
    nf0 = *(const float4*)&x[xr + lg * 8];
    nf1 = *(const float4*)&x[xr + lg * 8 + 4];
    if (lg < 3) {
      nf2 = *(const float4*)&x[xr + 32 + lg * 8];
      nf3 = *(const float4*)&x[xr + 32 + lg * 8 + 4];
    } else {
      nf2 = *(const float4*)&x[xr + 56];
      float4 t4 = *(const float4*)&x[xr + 59];
      nf3 = make_float4(t4.y, t4.z, t4.w, 0.f);
    }
  };
  auto cvt8 = [](const float4& a, const float4& b, s8v& hi, s8v& lo) {
    float v0[8] = {a.x, a.y, a.z, a.w, b.x, b.y, b.z, b.w};
    #pragma unroll
    for (int i = 0; i < 8; ++i) {
      ushort h = f2bf(v0[i]);
      hi[i] = (short)h;
      lo[i] = (short)f2bf(v0[i] - bf2f(h));
    }
  };

  s8v xch[2], xcl[2];
  loadx(t0);
  cvt8(nf0, nf1, xch[0], xcl[0]);
  cvt8(nf2, nf3, xch[1], xcl[1]);
  __syncthreads();

  const long sbase = (b0 + lr) * 128 + u0;   // h-stream slot (stride 524288/step)
  ushort4 st_h, st_l;                        // deferred-store payload

  int pp = 0;
  for (int s = 0; s < tc; ++s, pp ^= 1) {
    // deferred global store of step s-1's h (gets a full step of cover)
    if (s > 0) {
      *(ushort4*)&s_hi[sbase + (long)(s - 1) * 524288] = st_h;
      *(ushort4*)&s_lo[sbase + (long)(s - 1) * 524288] = st_l;
    }
    if (s + 1 < tc) loadx(t0 + s + 1);
    f4v ar = {0.f, 0.f, 0.f, 0.f}, az = ar, anx = ar, anh = ar;
    #pragma unroll
    for (int kt = 0; kt < 4; ++kt) {
      int ba = lr * 256 + ((kt * 64 + lg * 16) ^ ((lr & 7) << 4));
      s8v Ah = *(const s8v*)((const char*)hh_[pp] + ba);
      s8v Al = *(const s8v*)((const char*)hl_[pp] + ba);
      MF(Bb[(0 * 4 + kt) * 2 + 0], Ah, ar);
      MF(Bb[(1 * 4 + kt) * 2 + 0], Ah, az);
      MF(Bb[(2 * 4 + kt) * 2 + 0], Ah, anh);
      MF(Bb[(0 * 4 + kt) * 2 + 1], Ah, ar);
      MF(Bb[(1 * 4 + kt) * 2 + 1], Ah, az);
      MF(Bb[(2 * 4 + kt) * 2 + 1], Ah, anh);
      MF(Bb[(0 * 4 + kt) * 2 + 0], Al, ar);
      MF(Bb[(1 * 4 + kt) * 2 + 0], Al, az);
      MF(Bb[(2 * 4 + kt) * 2 + 0], Al, anh);
    }
    #pragma unroll
    for (int kt = 0; kt < 2; ++kt) {
      MF(Ba[(0 * 2 + kt) * 2 + 0], xch[kt], ar);
      MF(Ba[(1 * 2 + kt) * 2 + 0], xch[kt], az);
      MF(Ba[(2 * 2 + kt) * 2 + 0], xch[kt], anx);
      MF(Ba[(0 * 2 + kt) * 2 + 1], xch[kt], ar);
      MF(Ba[(1 * 2 + kt) * 2 + 1], xch[kt], az);
      MF(Ba[(2 * 2 + kt) * 2 + 1], xch[kt], anx);
      MF(Ba[(0 * 2 + kt) * 2 + 0], xcl[kt], ar);
      MF(Ba[(1 * 2 + kt) * 2 + 0], xcl[kt], az);
      MF(Ba[(2 * 2 + kt) * 2 + 0], xcl[kt], anx);
    }
    // in-register pointwise: row lr, units u0..u0+3
    {
      ushort4 oh = *(const ushort4*)((const char*)hh_[pp] + hb);
      ushort4 ol = *(const ushort4*)((const char*)hl_[pp] + hb);
      f4v vbr = *(const f4v*)&bb[u0];
      f4v vbz = *(const f4v*)&bb[128 + u0];
      f4v vbx = *(const f4v*)&bb[256 + u0];
      f4v vbh = *(const f4v*)&bb[384 + u0];
      const ushort* ohp = (const ushort*)&oh;
      const ushort* olp = (const ushort*)&ol;
      ushort nh_[4], nl_[4];
      #pragma unroll
      for (int j = 0; j < 4; ++j) {
        float hold = bf2f(ohp[j]) + bf2f(olp[j]);
        float rg = sigm(ar[j] + vbr[j]);
        float zg = sigm(az[j] + vbz[j]);
        float ng = tanh_safe(anx[j] + vbx[j] + rg * (anh[j] + vbh[j]));
        float hn = (1.f - zg) * ng + zg * hold;
        ushort hbf = f2bf(hn);
        nh_[j] = hbf; nl_[j] = f2bf(hn - bf2f(hbf));
      }
      ushort4 wh = make_ushort4(nh_[0], nh_[1], nh_[2], nh_[3]);
      ushort4 wl = make_ushort4(nl_[0], nl_[1], nl_[2], nl_[3]);
      *(ushort4*)((char*)hh_[pp ^ 1] + hb) = wh;
      *(ushort4*)((char*)hl_[pp ^ 1] + hb) = wl;
      st_h = wh; st_l = wl;                   // store deferred to next iteration
    }
    if (s + 1 < tc) {                         // convert prefetched x (loads have landed)
      cvt8(nf0, nf1, xch[0], xcl[0]);
      cvt8(nf2, nf3, xch[1], xcl[1]);
    }
    __syncthreads();
  }
  // flush last step's h-stream slot + carry state
  *(ushort4*)&s_hi[sbase + (long)(tc - 1) * 524288] = st_h;
  *(ushort4*)&s_lo[sbase + (long)(tc - 1) * 524288] = st_l;
  *(ushort4*)&c_hi[(b0 + lr) * 128 + u0] = *(const ushort4*)((const char*)hh_[pp] + hb);
  *(ushort4*)&c_lo[(b0 + lr) * 128 + u0] = *(const ushort4*)((const char*)hl_[pp] + hb);
}

// ---------- layer 1: h0 input staged global->reg->swizzled LDS (R5-exact) ----------
__global__ void __attribute__((amdgpu_flat_work_group_size(512, 512),
                               amdgpu_waves_per_eu(2, 2)))
rec_l1(const ushort* __restrict__ s_hi, const ushort* __restrict__ s_lo,
       const ushort* __restrict__ fih, const ushort* __restrict__ fhh,
       const float* __restrict__ bi, const float* __restrict__ bh,
       ushort* __restrict__ c_hi, ushort* __restrict__ c_lo,
       float* __restrict__ h1f, int tc, int first, int last)
{
  __shared__ __align__(16) ushort hh_[2][2048], hl_[2][2048];  // h1 state (swizzled)
  __shared__ __align__(16) ushort gh_[2][2048], gl_[2][2048];  // staged h0 (swizzled)
  __shared__ __align__(16) float bb[512];
  const int tid = threadIdx.x;
  const int l = tid & 63, wv = tid >> 6;
  const int lr = l & 15, lg = l >> 4;
  const long b0 = (long)blockIdx.x * 16;

  if (tid < 128) {
    bb[tid]       = bi[tid] + bh[tid];
    bb[128 + tid] = bi[128 + tid] + bh[128 + tid];
    bb[256 + tid] = bi[256 + tid];
    bb[384 + tid] = bh[256 + tid];
  }
  const int u0 = (wv << 4) + (lg << 2);
  const int hb = lr * 256 + ((u0 << 1) ^ ((lr & 7) << 4));
  if (first) {
    *(ushort4*)((char*)hh_[0] + hb) = make_ushort4(0, 0, 0, 0);
    *(ushort4*)((char*)hl_[0] + hb) = make_ushort4(0, 0, 0, 0);
  } else {
    *(ushort4*)((char*)hh_[0] + hb) = *(const ushort4*)&c_hi[(b0 + lr) * 128 + u0];
    *(ushort4*)((char*)hl_[0] + hb) = *(const ushort4*)&c_lo[(b0 + lr) * 128 + u0];
  }

  // staging assignment: tid<256 -> hi plane, else lo; 16 B per thread per step
  const int stid = tid & 255;
  const int srow = stid >> 4, sc16 = stid & 15;
  const int sdst = srow * 256 + ((sc16 * 16) ^ ((srow & 7) << 4));   // bytes in 4KB tile
  const ushort* ssel = (tid < 256) ? s_hi : s_lo;
  ushort* dsel = (tid < 256) ? &gh_[0][0] : &gl_[0][0];

  // parked weight frags
  s8v Ba[24], Bb[24];
  #pragma unroll
  for (int gi = 0; gi < 3; ++gi) {
    int nt = wv + 8 * gi;
    #pragma unroll
    for (int kt = 0; kt < 4; ++kt)
      #pragma unroll
      for (int hl = 0; hl < 2; ++hl) {
        Ba[(gi * 4 + kt) * 2 + hl] = *(const s8v*)&fih[((long)((nt * 4 + kt) * 2 + hl)) * 512 + l * 8];
        Bb[(gi * 4 + kt) * 2 + hl] = *(const s8v*)&fhh[((long)((nt * 4 + kt) * 2 + hl)) * 512 + l * 8];
      }
  }
  // prologue: stage tile 0
  {
    s8v v = *(const s8v*)&ssel[((long)0 * 4096 + b0 + srow) * 128 + sc16 * 8];
    *(s8v*)((char*)(dsel + 0 * 2048) + sdst) = v;
  }
  __syncthreads();

  int pp = 0;
  for (int tl = 0; tl < tc; ++tl, pp ^= 1) {
    s8v sreg;
    const int havenext = (tl + 1 < tc);
    if (havenext)
      sreg = *(const s8v*)&ssel[((long)(tl + 1) * 4096 + b0 + srow) * 128 + sc16 * 8];

    f4v ar = {0.f, 0.f, 0.f, 0.f}, az = ar, anx = ar, anh = ar;
    #pragma unroll
    for (int kt = 0; kt < 4; ++kt) {
      int ba = lr * 256 + ((kt * 64 + lg * 16) ^ ((lr & 7) << 4));
      s8v Hh = *(const s8v*)((const char*)hh_[pp] + ba);
      s8v Hl = *(const s8v*)((const char*)hl_[pp] + ba);
      s8v Gh = *(const s8v*)((const char*)gh_[pp] + ba);
      s8v Gl = *(const s8v*)((const char*)gl_[pp] + ba);
      MF(Bb[(0 * 4 + kt) * 2 + 0], Hh, ar);
      MF(Ba[(0 * 4 + kt) * 2 + 0], Gh, ar);
      MF(Bb[(1 * 4 + kt) * 2 + 0], Hh, az);
      MF(Ba[(1 * 4 + kt) * 2 + 0], Gh, az);
      MF(Bb[(2 * 4 + kt) * 2 + 0], Hh, anh);
      MF(Ba[(2 * 4 + kt) * 2 + 0], Gh, anx);
      MF(Bb[(0 * 4 + kt) * 2 + 1], Hh, ar);
      MF(Ba[(0 * 4 + kt) * 2 + 1], Gh, ar);
      MF(Bb[(1 * 4 + kt) * 2 + 1], Hh, az);
      MF(Ba[(1 * 4 + kt) * 2 + 1], Gh, az);
      MF(Bb[(2 * 4 + kt) * 2 + 1], Hh, anh);
      MF(Ba[(2 * 4 + kt) * 2 + 1], Gh, anx);
      MF(Bb[(0 * 4 + kt) * 2 + 0], Hl, ar);
      MF(Ba[(0 * 4 + kt) * 2 + 0], Gl, ar);
      MF(Bb[(1 * 4 + kt) * 2 + 0], Hl, az);
      MF(Ba[(1 * 4 + kt) * 2 + 0], Gl, az);
      MF(Bb[(2 * 4 + kt) * 2 + 0], Hl, anh);
      MF(Ba[(2 * 4 + kt) * 2 + 0], Gl, anx);
    }
    {
      ushort4 oh = *(const ushort4*)((const char*)hh_[pp] + hb);
      ushort4 ol = *(const ushort4*)((const char*)hl_[pp] + hb);
      f4v vbr = *(const f4v*)&bb[u0];
      f4v vbz = *(const f4v*)&bb[128 + u0];
      f4v vbx = *(const f4v*)&bb[256 + u0];
      f4v vbh = *(const f4v*)&bb[384 + u0];
      const ushort* ohp = (const ushort*)&oh;
      const ushort* olp = (const ushort*)&ol;
      ushort nh_[4], nl_[4];
      #pragma unroll
      for (int j = 0; j < 4; ++j) {
        float hold = bf2f(ohp[j]) + bf2f(olp[j]);
        float rg = sigm(ar[j] + vbr[j]);
        float zg = sigm(az[j] + vbz[j]);
        float ng = tanh_safe(anx[j] + vbx[j] + rg * (anh[j] + vbh[j]));
        float hn = (1.f - zg) * ng + zg * hold;
        ushort hbf = f2bf(hn);
        nh_[j] = hbf; nl_[j] = f2bf(hn - bf2f(hbf));
      }
      *(ushort4*)((char*)hh_[pp ^ 1] + hb) = make_ushort4(nh_[0], nh_[1], nh_[2], nh_[3]);
      *(ushort4*)((char*)hl_[pp ^ 1] + hb) = make_ushort4(nl_[0], nl_[1], nl_[2], nl_[3]);
    }
    if (havenext)
      *(s8v*)((char*)(dsel + (size_t)(pp ^ 1) * 2048) + sdst) = sreg;
    __syncthreads();
  }
  {
    ushort4 fh = *(const ushort4*)((const char*)hh_[pp] + hb);
    ushort4 fl = *(const ushort4*)((const char*)hl_[pp] + hb);
    *(ushort4*)&c_hi[(b0 + lr) * 128 + u0] = fh;
    *(ushort4*)&c_lo[(b0 + lr) * 128 + u0] = fl;
    if (last) {
      const ushort* fhp = (const ushort*)&fh;
      const ushort* flp = (const ushort*)&fl;
      float4 o;
      o.x = bf2f(fhp[0]) + bf2f(flp[0]);
      o.y = bf2f(fhp[1]) + bf2f(flp[1]);
      o.z = bf2f(fhp[2]) + bf2f(flp[2]);
      o.w = bf2f(fhp[3]) + bf2f(flp[3]);
      *(float4*)&h1f[(b0 + lr) * 128 + u0] = o;
    }
  }
}

// ---------- head: relu(h1 @ w1^T + b1) @ w2^T + b2 ----------
__global__ __launch_bounds__(512) void head_k(
    const float* __restrict__ h1f, const float* __restrict__ w1,
    const float* __restrict__ b1, const float* __restrict__ w2,
    const float* __restrict__ b2, float* __restrict__ out)
{
  __shared__ float hrow[16][132];
  __shared__ float w1s[64][132];
  __shared__ float hid[16][68];
  const int tid = threadIdx.x;
  const long b0 = (long)blockIdx.x * 16;
  for (int i = tid; i < 64 * 128; i += 512) w1s[i >> 7][i & 127] = w1[i];
  {
    int rr = tid >> 5, k4 = (tid & 31) * 4;
    *(float4*)&hrow[rr][k4] = *(const float4*)&h1f[(b0 + rr) * 128 + k4];
  }
  __syncthreads();
  {
    int r = tid & 15, fu = tid >> 4;
    float a0 = 0.f, a1 = 0.f;
    for (int k4 = 0; k4 < 32; ++k4) {
      float4 hv = *(const float4*)&hrow[r][k4 * 4];
      float4 wa = *(const float4*)&w1s[fu][k4 * 4];
      float4 wb = *(const float4*)&w1s[fu + 32][k4 * 4];
      a0 += dot4(wa, hv);
      a1 += dot4(wb, hv);
    }
    a0 += b1[fu]; a1 += b1[fu + 32];
    hid[r][fu]      = fmaxf(a0, 0.f);
    hid[r][fu + 32] = fmaxf(a1, 0.f);
  }
  __syncthreads();
  if (tid < 176) {
    int rr = tid / 11, c = tid - rr * 11;
    float acc = b2[c];
    for (int k = 0; k < 64; ++k) acc = fmaf(w2[c * 64 + k], hid[rr][k], acc);
    out[(b0 + rr) * 11 + c] = acc;
  }
}

extern "C" void kernel_launch(void* const* d_in, const int* in_sizes, int n_in,
                              void* d_out, int out_size, void* d_ws, size_t ws_size,
                              hipStream_t stream) {
  (void)in_sizes; (void)n_in; (void)out_size;
  const float* x    = (const float*)d_in[0];
  const float* wih0 = (const float*)d_in[1];
  const float* whh0 = (const float*)d_in[2];
  const float* bih0 = (const float*)d_in[3];
  const float* bhh0 = (const float*)d_in[4];
  const float* wih1 = (const float*)d_in[5];
  const float* whh1 = (const float*)d_in[6];
  const float* bih1 = (const float*)d_in[7];
  const float* bhh1 = (const float*)d_in[8];
  const float* w1   = (const float*)d_in[9];
  const float* b1   = (const float*)d_in[10];
  const float* w2   = (const float*)d_in[11];
  const float* b2   = (const float*)d_in[12];

  char* wsb = (char*)d_ws;
  size_t o = 0;
  ushort* fih0 = (ushort*)(wsb + o); o += 98304;
  ushort* fhh0 = (ushort*)(wsb + o); o += 196608;
  ushort* fih1 = (ushort*)(wsb + o); o += 196608;
  ushort* fhh1 = (ushort*)(wsb + o); o += 196608;
  ushort* hc0h = (ushort*)(wsb + o); o += 1048576;
  ushort* hc0l = (ushort*)(wsb + o); o += 1048576;
  ushort* hc1h = (ushort*)(wsb + o); o += 1048576;
  ushort* hc1l = (ushort*)(wsb + o); o += 1048576;
  float*  h1f  = (float*)(wsb + o);  o += 2097152;

  long rem = (long)ws_size - (long)o;
  long tcmax = rem / (2 * 1048576L);
  int Tc = tcmax > 128 ? 128 : (int)tcmax;
  if (Tc < 1) return;  // ws too small
  ushort* sh = (ushort*)(wsb + o);
  ushort* sl = sh + (long)Tc * 524288;

  hipLaunchKernelGGL(pack_fr, dim3(192), dim3(256), 0, stream, wih0, fih0, 63, 2, 49152);
  hipLaunchKernelGGL(pack_fr, dim3(384), dim3(256), 0, stream, whh0, fhh0, 128, 4, 98304);
  hipLaunchKernelGGL(pack_fr, dim3(384), dim3(256), 0, stream, wih1, fih1, 128, 4, 98304);
  hipLaunchKernelGGL(pack_fr, dim3(384), dim3(256), 0, stream, whh1, fhh1, 128, 4, 98304);

  for (int t0 = 0; t0 < 128; t0 += Tc) {
    int tc = (128 - t0) < Tc ? (128 - t0) : Tc;
    hipLaunchKernelGGL(rec_l0, dim3(256), dim3(512), 0, stream,
                       x, fih0, fhh0, bih0, bhh0, sh, sl, hc0h, hc0l,
                       t0, tc, (int)(t0 == 0));
    hipLaunchKernelGGL(rec_l1, dim3(256), dim3(512), 0, stream,
                       sh, sl, fih1, fhh1, bih1, bhh1, hc1h, hc1l, h1f,
                       tc, (int)(t0 == 0), (int)(t0 + tc == 128));
  }
  hipLaunchKernelGGL(head_k, dim3(256), dim3(512), 0, stream,
                     h1f, w1, b1, w2, b2, (float*)d_out);
}

// Round 11
// 652.587 us; speedup vs baseline: 1.5450x; 1.1504x over previous
//
#include <hip/hip_runtime.h>
#include <hip/hip_bf16.h>

typedef __attribute__((ext_vector_type(8))) short s8v;   // 8 bf16 = 4 VGPR
typedef __attribute__((ext_vector_type(4))) float f4v;   // MFMA acc

// A = weight frag, B = data frag  ->  C[m=unit][n=batch-row]
#define MF(A, B, C) C = __builtin_amdgcn_mfma_f32_16x16x32_bf16((A), (B), (C), 0, 0, 0)

__device__ __forceinline__ ushort f2bf(float f) {
  unsigned u = __float_as_uint(f);
  u += 0x7FFF + ((u >> 16) & 1);        // RNE (finite inputs only)
  return (ushort)(u >> 16);
}
__device__ __forceinline__ float bf2f(ushort h) {
  return __uint_as_float(((unsigned)h) << 16);
}
__device__ __forceinline__ float sigm(float p) { return 1.f / (1.f + __expf(-p)); }
__device__ __forceinline__ float tanh_safe(float a) {
  float t = __expf(-2.f * fabsf(a));
  float ng = (1.f - t) / (1.f + t);
  return a < 0.f ? -ng : ng;
}
__device__ __forceinline__ float dot4(float4 a, float4 b) {
  return fmaf(a.x, b.x, fmaf(a.y, b.y, fmaf(a.z, b.z, a.w * b.w)));
}

// ---------- pre-pass: split x into bf16 hi/lo, pad K 63->64 ----------
__global__ void conv_x(const float* __restrict__ x, ushort* __restrict__ xhi,
                       ushort* __restrict__ xlo, int total) {
  int idx = blockIdx.x * 256 + threadIdx.x;
  if (idx >= total) return;                    // total = 4096*128*16
  int k4 = (idx & 15) * 4;
  long bt = idx >> 4;
  #pragma unroll
  for (int j = 0; j < 4; ++j) {
    int k = k4 + j;
    float v = (k < 63) ? x[bt * 63 + k] : 0.f;
    ushort hi = f2bf(v);
    xhi[bt * 64 + k] = hi;
    xlo[bt * 64 + k] = f2bf(v - bf2f(hi));
  }
}

// ---------- pre-pass: pack W [384][Kreal] into per-lane frag streams (hi/lo) ----------
// frag_id = (nt*KT + kt)*2 + hl ; lane l elem i supplies W[nt*16+(l&15)][kt*32+(l>>4)*8+i]
__global__ void pack_fr(const float* __restrict__ src, ushort* __restrict__ dst,
                        int Kreal, int KT, int total) {
  int idx = blockIdx.x * 256 + threadIdx.x;
  if (idx >= total) return;
  int i = idx & 7, l = (idx >> 3) & 63, hl = (idx >> 9) & 1;
  int rest = idx >> 10;
  int kt = rest % KT, nt = rest / KT;
  int g = nt * 16 + (l & 15);
  int k = kt * 32 + (l >> 4) * 8 + i;
  float v = (k < Kreal) ? src[g * Kreal + k] : 0.f;
  ushort hi = f2bf(v);
  dst[idx] = hl ? f2bf(v - bf2f(hi)) : hi;
}

// ---------- layer 0: 16 rows/block, 8 waves, deferred h-stream stores ----------
__global__ void __attribute__((amdgpu_flat_work_group_size(512, 512),
                               amdgpu_waves_per_eu(2, 2)))
rec_l0(const ushort* __restrict__ xhi, const ushort* __restrict__ xlo,
       const ushort* __restrict__ fih, const ushort* __restrict__ fhh,
       const float* __restrict__ bi, const float* __restrict__ bh,
       ushort* __restrict__ s_hi, ushort* __restrict__ s_lo,
       ushort* __restrict__ c_hi, ushort* __restrict__ c_lo,
       int t0, int tc, int first)
{
  __shared__ __align__(16) ushort hh_[2][2048], hl_[2][2048];  // swizzled h state
  __shared__ __align__(16) float bb[512];
  const int tid = threadIdx.x;
  const int l = tid & 63, wv = tid >> 6;
  const int lr = l & 15, lg = l >> 4;
  const long b0 = (long)blockIdx.x * 16;

  if (tid < 128) {
    bb[tid]       = bi[tid] + bh[tid];
    bb[128 + tid] = bi[128 + tid] + bh[128 + tid];
    bb[256 + tid] = bi[256 + tid];
    bb[384 + tid] = bh[256 + tid];
  }
  const int u0 = (wv << 4) + (lg << 2);
  const int hb = lr * 256 + ((u0 << 1) ^ ((lr & 7) << 4));
  if (first) {
    *(ushort4*)((char*)hh_[0] + hb) = make_ushort4(0, 0, 0, 0);
    *(ushort4*)((char*)hl_[0] + hb) = make_ushort4(0, 0, 0, 0);
  } else {
    *(ushort4*)((char*)hh_[0] + hb) = *(const ushort4*)&c_hi[(b0 + lr) * 128 + u0];
    *(ushort4*)((char*)hl_[0] + hb) = *(const ushort4*)&c_lo[(b0 + lr) * 128 + u0];
  }

  // parked weight frags: gate gi -> nt = wv + 8*gi
  s8v Ba[12];   // ih [(gi*2+kt)*2+hl]
  s8v Bb[24];   // hh [(gi*4+kt)*2+hl]
  #pragma unroll
  for (int gi = 0; gi < 3; ++gi) {
    int nt = wv + 8 * gi;
    #pragma unroll
    for (int kt = 0; kt < 2; ++kt)
      #pragma unroll
      for (int hl = 0; hl < 2; ++hl)
        Ba[(gi * 2 + kt) * 2 + hl] = *(const s8v*)&fih[((long)((nt * 2 + kt) * 2 + hl)) * 512 + l * 8];
    #pragma unroll
    for (int kt = 0; kt < 4; ++kt)
      #pragma unroll
      for (int hl = 0; hl < 2; ++hl)
        Bb[(gi * 4 + kt) * 2 + hl] = *(const s8v*)&fhh[((long)((nt * 4 + kt) * 2 + hl)) * 512 + l * 8];
  }

  // x register double-buffer (B-frags: lane lr=row, k=(lg*8..)+kt*32)
  s8v xch[2], xcl[2], xnh[2], xnl[2];
  {
    long xo = ((b0 + lr) * 128 + t0) * 64 + lg * 8;
    xch[0] = *(const s8v*)&xhi[xo]; xch[1] = *(const s8v*)&xhi[xo + 32];
    xcl[0] = *(const s8v*)&xlo[xo]; xcl[1] = *(const s8v*)&xlo[xo + 32];
  }
  __syncthreads();

  const long sbase = (b0 + lr) * 128 + u0;   // h-stream slot (stride 524288/step)
  ushort4 st_h, st_l;                        // deferred-store payload

  int pp = 0;
  for (int s = 0; s < tc; ++s, pp ^= 1) {
    // deferred global store of step s-1's h (gets a full step of cover)
    if (s > 0) {
      *(ushort4*)&s_hi[sbase + (long)(s - 1) * 524288] = st_h;
      *(ushort4*)&s_lo[sbase + (long)(s - 1) * 524288] = st_l;
    }
    if (s + 1 < tc) {
      long xo = ((b0 + lr) * 128 + (t0 + s + 1)) * 64 + lg * 8;
      xnh[0] = *(const s8v*)&xhi[xo]; xnh[1] = *(const s8v*)&xhi[xo + 32];
      xnl[0] = *(const s8v*)&xlo[xo]; xnl[1] = *(const s8v*)&xlo[xo + 32];
    }
    f4v ar = {0.f, 0.f, 0.f, 0.f}, az = ar, anx = ar, anh = ar;
    #pragma unroll
    for (int kt = 0; kt < 4; ++kt) {
      int ba = lr * 256 + ((kt * 64 + lg * 16) ^ ((lr & 7) << 4));
      s8v Ah = *(const s8v*)((const char*)hh_[pp] + ba);
      s8v Al = *(const s8v*)((const char*)hl_[pp] + ba);
      MF(Bb[(0 * 4 + kt) * 2 + 0], Ah, ar);
      MF(Bb[(1 * 4 + kt) * 2 + 0], Ah, az);
      MF(Bb[(2 * 4 + kt) * 2 + 0], Ah, anh);
      MF(Bb[(0 * 4 + kt) * 2 + 1], Ah, ar);
      MF(Bb[(1 * 4 + kt) * 2 + 1], Ah, az);
      MF(Bb[(2 * 4 + kt) * 2 + 1], Ah, anh);
      MF(Bb[(0 * 4 + kt) * 2 + 0], Al, ar);
      MF(Bb[(1 * 4 + kt) * 2 + 0], Al, az);
      MF(Bb[(2 * 4 + kt) * 2 + 0], Al, anh);
    }
    #pragma unroll
    for (int kt = 0; kt < 2; ++kt) {
      MF(Ba[(0 * 2 + kt) * 2 + 0], xch[kt], ar);
      MF(Ba[(1 * 2 + kt) * 2 + 0], xch[kt], az);
      MF(Ba[(2 * 2 + kt) * 2 + 0], xch[kt], anx);
      MF(Ba[(0 * 2 + kt) * 2 + 1], xch[kt], ar);
      MF(Ba[(1 * 2 + kt) * 2 + 1], xch[kt], az);
      MF(Ba[(2 * 2 + kt) * 2 + 1], xch[kt], anx);
      MF(Ba[(0 * 2 + kt) * 2 + 0], xcl[kt], ar);
      MF(Ba[(1 * 2 + kt) * 2 + 0], xcl[kt], az);
      MF(Ba[(2 * 2 + kt) * 2 + 0], xcl[kt], anx);
    }
    // in-register pointwise: row lr, units u0..u0+3
    {
      ushort4 oh = *(const ushort4*)((const char*)hh_[pp] + hb);
      ushort4 ol = *(const ushort4*)((const char*)hl_[pp] + hb);
      f4v vbr = *(const f4v*)&bb[u0];
      f4v vbz = *(const f4v*)&bb[128 + u0];
      f4v vbx = *(const f4v*)&bb[256 + u0];
      f4v vbh = *(const f4v*)&bb[384 + u0];
      const ushort* ohp = (const ushort*)&oh;
      const ushort* olp = (const ushort*)&ol;
      ushort nh_[4], nl_[4];
      #pragma unroll
      for (int j = 0; j < 4; ++j) {
        float hold = bf2f(ohp[j]) + bf2f(olp[j]);
        float rg = sigm(ar[j] + vbr[j]);
        float zg = sigm(az[j] + vbz[j]);
        float ng = tanh_safe(anx[j] + vbx[j] + rg * (anh[j] + vbh[j]));
        float hn = (1.f - zg) * ng + zg * hold;
        ushort hbf = f2bf(hn);
        nh_[j] = hbf; nl_[j] = f2bf(hn - bf2f(hbf));
      }
      ushort4 wh = make_ushort4(nh_[0], nh_[1], nh_[2], nh_[3]);
      ushort4 wl = make_ushort4(nl_[0], nl_[1], nl_[2], nl_[3]);
      *(ushort4*)((char*)hh_[pp ^ 1] + hb) = wh;
      *(ushort4*)((char*)hl_[pp ^ 1] + hb) = wl;
      st_h = wh; st_l = wl;                   // store deferred to next iteration
    }
    xch[0] = xnh[0]; xch[1] = xnh[1]; xcl[0] = xnl[0]; xcl[1] = xnl[1];
    __syncthreads();
  }
  // flush last step's h-stream slot + carry state
  *(ushort4*)&s_hi[sbase + (long)(tc - 1) * 524288] = st_h;
  *(ushort4*)&s_lo[sbase + (long)(tc - 1) * 524288] = st_l;
  *(ushort4*)&c_hi[(b0 + lr) * 128 + u0] = *(const ushort4*)((const char*)hh_[pp] + hb);
  *(ushort4*)&c_lo[(b0 + lr) * 128 + u0] = *(const ushort4*)((const char*)hl_[pp] + hb);
}

// ---------- layer 1: h0 input staged global->reg->swizzled LDS (R5-exact) ----------
__global__ void __attribute__((amdgpu_flat_work_group_size(512, 512),
                               amdgpu_waves_per_eu(2, 2)))
rec_l1(const ushort* __restrict__ s_hi, const ushort* __restrict__ s_lo,
       const ushort* __restrict__ fih, const ushort* __restrict__ fhh,
       const float* __restrict__ bi, const float* __restrict__ bh,
       ushort* __restrict__ c_hi, ushort* __restrict__ c_lo,
       float* __restrict__ h1f, int tc, int first, int last)
{
  __shared__ __align__(16) ushort hh_[2][2048], hl_[2][2048];  // h1 state (swizzled)
  __shared__ __align__(16) ushort gh_[2][2048], gl_[2][2048];  // staged h0 (swizzled)
  __shared__ __align__(16) float bb[512];
  const int tid = threadIdx.x;
  const int l = tid & 63, wv = tid >> 6;
  const int lr = l & 15, lg = l >> 4;
  const long b0 = (long)blockIdx.x * 16;

  if (tid < 128) {
    bb[tid]       = bi[tid] + bh[tid];
    bb[128 + tid] = bi[128 + tid] + bh[128 + tid];
    bb[256 + tid] = bi[256 + tid];
    bb[384 + tid] = bh[256 + tid];
  }
  const int u0 = (wv << 4) + (lg << 2);
  const int hb = lr * 256 + ((u0 << 1) ^ ((lr & 7) << 4));
  if (first) {
    *(ushort4*)((char*)hh_[0] + hb) = make_ushort4(0, 0, 0, 0);
    *(ushort4*)((char*)hl_[0] + hb) = make_ushort4(0, 0, 0, 0);
  } else {
    *(ushort4*)((char*)hh_[0] + hb) = *(const ushort4*)&c_hi[(b0 + lr) * 128 + u0];
    *(ushort4*)((char*)hl_[0] + hb) = *(const ushort4*)&c_lo[(b0 + lr) * 128 + u0];
  }

  // staging assignment: tid<256 -> hi plane, else lo; 16 B per thread per step
  const int stid = tid & 255;
  const int srow = stid >> 4, sc16 = stid & 15;
  const int sdst = srow * 256 + ((sc16 * 16) ^ ((srow & 7) << 4));   // bytes in 4KB tile
  const ushort* ssel = (tid < 256) ? s_hi : s_lo;
  ushort* dsel = (tid < 256) ? &gh_[0][0] : &gl_[0][0];

  // parked weight frags
  s8v Ba[24], Bb[24];
  #pragma unroll
  for (int gi = 0; gi < 3; ++gi) {
    int nt = wv + 8 * gi;
    #pragma unroll
    for (int kt = 0; kt < 4; ++kt)
      #pragma unroll
      for (int hl = 0; hl < 2; ++hl) {
        Ba[(gi * 4 + kt) * 2 + hl] = *(const s8v*)&fih[((long)((nt * 4 + kt) * 2 + hl)) * 512 + l * 8];
        Bb[(gi * 4 + kt) * 2 + hl] = *(const s8v*)&fhh[((long)((nt * 4 + kt) * 2 + hl)) * 512 + l * 8];
      }
  }
  // prologue: stage tile 0
  {
    s8v v = *(const s8v*)&ssel[((long)0 * 4096 + b0 + srow) * 128 + sc16 * 8];
    *(s8v*)((char*)(dsel + 0 * 2048) + sdst) = v;
  }
  __syncthreads();

  int pp = 0;
  for (int tl = 0; tl < tc; ++tl, pp ^= 1) {
    s8v sreg;
    const int havenext = (tl + 1 < tc);
    if (havenext)
      sreg = *(const s8v*)&ssel[((long)(tl + 1) * 4096 + b0 + srow) * 128 + sc16 * 8];

    f4v ar = {0.f, 0.f, 0.f, 0.f}, az = ar, anx = ar, anh = ar;
    #pragma unroll
    for (int kt = 0; kt < 4; ++kt) {
      int ba = lr * 256 + ((kt * 64 + lg * 16) ^ ((lr & 7) << 4));
      s8v Hh = *(const s8v*)((const char*)hh_[pp] + ba);
      s8v Hl = *(const s8v*)((const char*)hl_[pp] + ba);
      s8v Gh = *(const s8v*)((const char*)gh_[pp] + ba);
      s8v Gl = *(const s8v*)((const char*)gl_[pp] + ba);
      MF(Bb[(0 * 4 + kt) * 2 + 0], Hh, ar);
      MF(Ba[(0 * 4 + kt) * 2 + 0], Gh, ar);
      MF(Bb[(1 * 4 + kt) * 2 + 0], Hh, az);
      MF(Ba[(1 * 4 + kt) * 2 + 0], Gh, az);
      MF(Bb[(2 * 4 + kt) * 2 + 0], Hh, anh);
      MF(Ba[(2 * 4 + kt) * 2 + 0], Gh, anx);
      MF(Bb[(0 * 4 + kt) * 2 + 1], Hh, ar);
      MF(Ba[(0 * 4 + kt) * 2 + 1], Gh, ar);
      MF(Bb[(1 * 4 + kt) * 2 + 1], Hh, az);
      MF(Ba[(1 * 4 + kt) * 2 + 1], Gh, az);
      MF(Bb[(2 * 4 + kt) * 2 + 1], Hh, anh);
      MF(Ba[(2 * 4 + kt) * 2 + 1], Gh, anx);
      MF(Bb[(0 * 4 + kt) * 2 + 0], Hl, ar);
      MF(Ba[(0 * 4 + kt) * 2 + 0], Gl, ar);
      MF(Bb[(1 * 4 + kt) * 2 + 0], Hl, az);
      MF(Ba[(1 * 4 + kt) * 2 + 0], Gl, az);
      MF(Bb[(2 * 4 + kt) * 2 + 0], Hl, anh);
      MF(Ba[(2 * 4 + kt) * 2 + 0], Gl, anx);
    }
    {
      ushort4 oh = *(const ushort4*)((const char*)hh_[pp] + hb);
      ushort4 ol = *(const ushort4*)((const char*)hl_[pp] + hb);
      f4v vbr = *(const f4v*)&bb[u0];
      f4v vbz = *(const f4v*)&bb[128 + u0];
      f4v vbx = *(const f4v*)&bb[256 + u0];
      f4v vbh = *(const f4v*)&bb[384 + u0];
      const ushort* ohp = (const ushort*)&oh;
      const ushort* olp = (const ushort*)&ol;
      ushort nh_[4], nl_[4];
      #pragma unroll
      for (int j = 0; j < 4; ++j) {
        float hold = bf2f(ohp[j]) + bf2f(olp[j]);
        float rg = sigm(ar[j] + vbr[j]);
        float zg = sigm(az[j] + vbz[j]);
        float ng = tanh_safe(anx[j] + vbx[j] + rg * (anh[j] + vbh[j]));
        float hn = (1.f - zg) * ng + zg * hold;
        ushort hbf = f2bf(hn);
        nh_[j] = hbf; nl_[j] = f2bf(hn - bf2f(hbf));
      }
      *(ushort4*)((char*)hh_[pp ^ 1] + hb) = make_ushort4(nh_[0], nh_[1], nh_[2], nh_[3]);
      *(ushort4*)((char*)hl_[pp ^ 1] + hb) = make_ushort4(nl_[0], nl_[1], nl_[2], nl_[3]);
    }
    if (havenext)
      *(s8v*)((char*)(dsel + (size_t)(pp ^ 1) * 2048) + sdst) = sreg;
    __syncthreads();
  }
  {
    ushort4 fh = *(const ushort4*)((const char*)hh_[pp] + hb);
    ushort4 fl = *(const ushort4*)((const char*)hl_[pp] + hb);
    *(ushort4*)&c_hi[(b0 + lr) * 128 + u0] = fh;
    *(ushort4*)&c_lo[(b0 + lr) * 128 + u0] = fl;
    if (last) {
      const ushort* fhp = (const ushort*)&fh;
      const ushort* flp = (const ushort*)&fl;
      float4 o;
      o.x = bf2f(fhp[0]) + bf2f(flp[0]);
      o.y = bf2f(fhp[1]) + bf2f(flp[1]);
      o.z = bf2f(fhp[2]) + bf2f(flp[2]);
      o.w = bf2f(fhp[3]) + bf2f(flp[3]);
      *(float4*)&h1f[(b0 + lr) * 128 + u0] = o;
    }
  }
}

// ---------- head: relu(h1 @ w1^T + b1) @ w2^T + b2 ----------
__global__ __launch_bounds__(512) void head_k(
    const float* __restrict__ h1f, const float* __restrict__ w1,
    const float* __restrict__ b1, const float* __restrict__ w2,
    const float* __restrict__ b2, float* __restrict__ out)
{
  __shared__ float hrow[16][132];
  __shared__ float w1s[64][132];
  __shared__ float hid[16][68];
  const int tid = threadIdx.x;
  const long b0 = (long)blockIdx.x * 16;
  for (int i = tid; i < 64 * 128; i += 512) w1s[i >> 7][i & 127] = w1[i];
  {
    int rr = tid >> 5, k4 = (tid & 31) * 4;
    *(float4*)&hrow[rr][k4] = *(const float4*)&h1f[(b0 + rr) * 128 + k4];
  }
  __syncthreads();
  {
    int r = tid & 15, fu = tid >> 4;
    float a0 = 0.f, a1 = 0.f;
    for (int k4 = 0; k4 < 32; ++k4) {
      float4 hv = *(const float4*)&hrow[r][k4 * 4];
      float4 wa = *(const float4*)&w1s[fu][k4 * 4];
      float4 wb = *(const float4*)&w1s[fu + 32][k4 * 4];
      a0 += dot4(wa, hv);
      a1 += dot4(wb, hv);
    }
    a0 += b1[fu]; a1 += b1[fu + 32];
    hid[r][fu]      = fmaxf(a0, 0.f);
    hid[r][fu + 32] = fmaxf(a1, 0.f);
  }
  __syncthreads();
  if (tid < 176) {
    int rr = tid / 11, c = tid - rr * 11;
    float acc = b2[c];
    for (int k = 0; k < 64; ++k) acc = fmaf(w2[c * 64 + k], hid[rr][k], acc);
    out[(b0 + rr) * 11 + c] = acc;
  }
}

extern "C" void kernel_launch(void* const* d_in, const int* in_sizes, int n_in,
                              void* d_out, int out_size, void* d_ws, size_t ws_size,
                              hipStream_t stream) {
  (void)in_sizes; (void)n_in; (void)out_size;
  const float* x    = (const float*)d_in[0];
  const float* wih0 = (const float*)d_in[1];
  const float* whh0 = (const float*)d_in[2];
  const float* bih0 = (const float*)d_in[3];
  const float* bhh0 = (const float*)d_in[4];
  const float* wih1 = (const float*)d_in[5];
  const float* whh1 = (const float*)d_in[6];
  const float* bih1 = (const float*)d_in[7];
  const float* bhh1 = (const float*)d_in[8];
  const float* w1   = (const float*)d_in[9];
  const float* b1   = (const float*)d_in[10];
  const float* w2   = (const float*)d_in[11];
  const float* b2   = (const float*)d_in[12];

  char* wsb = (char*)d_ws;
  size_t o = 0;
  ushort* fih0 = (ushort*)(wsb + o); o += 98304;
  ushort* fhh0 = (ushort*)(wsb + o); o += 196608;
  ushort* fih1 = (ushort*)(wsb + o); o += 196608;
  ushort* fhh1 = (ushort*)(wsb + o); o += 196608;
  ushort* xhi  = (ushort*)(wsb + o); o += 67108864ULL;
  ushort* xlo  = (ushort*)(wsb + o); o += 67108864ULL;
  ushort* hc0h = (ushort*)(wsb + o); o += 1048576;
  ushort* hc0l = (ushort*)(wsb + o); o += 1048576;
  ushort* hc1h = (ushort*)(wsb + o); o += 1048576;
  ushort* hc1l = (ushort*)(wsb + o); o += 1048576;
  float*  h1f  = (float*)(wsb + o);  o += 2097152;

  long rem = (long)ws_size - (long)o;
  long tcmax = rem / (2 * 1048576L);
  int Tc = tcmax > 128 ? 128 : (int)tcmax;
  if (Tc < 1) return;  // ws too small
  ushort* sh = (ushort*)(wsb + o);
  ushort* sl = sh + (long)Tc * 524288;

  hipLaunchKernelGGL(conv_x, dim3(32768), dim3(256), 0, stream, x, xhi, xlo, 8388608);
  hipLaunchKernelGGL(pack_fr, dim3(192), dim3(256), 0, stream, wih0, fih0, 63, 2, 49152);
  hipLaunchKernelGGL(pack_fr, dim3(384), dim3(256), 0, stream, whh0, fhh0, 128, 4, 98304);
  hipLaunchKernelGGL(pack_fr, dim3(384), dim3(256), 0, stream, wih1, fih1, 128, 4, 98304);
  hipLaunchKernelGGL(pack_fr, dim3(384), dim3(256), 0, stream, whh1, fhh1, 128, 4, 98304);

  for (int t0 = 0; t0 < 128; t0 += Tc) {
    int tc = (128 - t0) < Tc ? (128 - t0) : Tc;
    hipLaunchKernelGGL(rec_l0, dim3(256), dim3(512), 0, stream,
                       xhi, xlo, fih0, fhh0, bih0, bhh0, sh, sl, hc0h, hc0l,
                       t0, tc, (int)(t0 == 0));
    hipLaunchKernelGGL(rec_l1, dim3(256), dim3(512), 0, stream,
                       sh, sl, fih1, fhh1, bih1, bhh1, hc1h, hc1l, h1f,
                       tc, (int)(t0 == 0), (int)(t0 + tc == 128));
  }
  hipLaunchKernelGGL(head_k, dim3(256), dim3(512), 0, stream,
                     h1f, w1, b1, w2, b2, (float*)d_out);
}